// Round 1
// baseline (6691.991 us; speedup 1.0000x reference)
//
#include <hip/hip_runtime.h>
#include <math.h>

#define NB 32
#define SS 512
#define S2 514
#define DD 256
#define HH 1024
#define MS (NB*S2)                     // 16448
#define MD ((size_t)MS*DD)             // 4,210,688
#define MD5 ((size_t)MS*DD*5)          // 21,053,440
#define MH ((size_t)MS*HH)             // 16,842,752
#define EPSF 1e-9f
#define NSTEPS 6

__device__ __forceinline__ float gelu_f(float x){
  float t = tanhf(0.7978845608028654f*(x + 0.044715f*x*x*x));
  return 0.5f*x*(1.f+t);
}
__device__ __forceinline__ float sigmoid_f(float x){ return 1.f/(1.f+expf(-x)); }

// Build seq0: [START, sequence, END-at-513] (mask is all-ones => static structure)
__global__ void k_build_seq0(const float* __restrict__ seq_in, const float* __restrict__ START,
                             const float* __restrict__ END, float* __restrict__ out){
  int m = blockIdx.x; int d = threadIdx.x;
  int s = m % S2; int b = m / S2;
  float v;
  if (s == 0)        v = START[d];
  else if (s <= SS)  v = seq_in[((size_t)(b*SS + (s-1)))*DD + d];
  else               v = END[d];
  out[(size_t)m*DD + d] = v;
}

__global__ void k_init_state(float* __restrict__ ltp, float* __restrict__ act){
  int i = blockIdx.x*256 + threadIdx.x;
  if (i < MS){ ltp[i]=0.f; act[i]=1.f; }
}

// Generic f32 GEMM: C = op(A@B + bias). A row-major MxK (optionally split into two
// source arrays along K for the [left_child | seq] concat), B row-major KxN.
// Tile 64x64, BK=16, 256 threads, 4x4 per thread. M%64==0, N%64==0, K%16==0.
template<int ACT, bool SPLIT>
__global__ __launch_bounds__(256) void k_sgemm(
    const float* __restrict__ A0, const float* __restrict__ A1, int splitK,
    const float* __restrict__ B, const float* __restrict__ bias,
    float* __restrict__ C, int M, int N, int K)
{
  __shared__ float As[16][64];
  __shared__ float Bs[16][64];
  const int tid = threadIdx.x;
  const int tx = tid & 15, ty = tid >> 4;
  const int m0 = blockIdx.x * 64, n0 = blockIdx.y * 64;
  const int arow = tid >> 2, ak4 = (tid & 3) << 2;
  const int brow = ty, bn4 = tx << 2;

  float acc[4][4];
#pragma unroll
  for (int i=0;i<4;i++){
#pragma unroll
    for (int j=0;j<4;j++) acc[i][j]=0.f;
  }

  for (int k0 = 0; k0 < K; k0 += 16){
    float4 av, bv;
    int gk = k0 + ak4;
    int gm = m0 + arow;
    if (!SPLIT){
      av = *reinterpret_cast<const float4*>(A0 + (size_t)gm*K + gk);
    } else {
      if (gk < splitK) av = *reinterpret_cast<const float4*>(A0 + (size_t)gm*splitK + gk);
      else             av = *reinterpret_cast<const float4*>(A1 + (size_t)gm*(K-splitK) + (gk - splitK));
    }
    bv = *reinterpret_cast<const float4*>(B + (size_t)(k0+brow)*N + n0 + bn4);
    __syncthreads();
    As[ak4+0][arow]=av.x; As[ak4+1][arow]=av.y; As[ak4+2][arow]=av.z; As[ak4+3][arow]=av.w;
    *reinterpret_cast<float4*>(&Bs[brow][bn4]) = bv;
    __syncthreads();
#pragma unroll
    for (int kk=0; kk<16; ++kk){
      float4 a4 = *reinterpret_cast<const float4*>(&As[kk][ty<<2]);
      float4 b4 = *reinterpret_cast<const float4*>(&Bs[kk][tx<<2]);
      float ar[4] = {a4.x,a4.y,a4.z,a4.w};
      float br[4] = {b4.x,b4.y,b4.z,b4.w};
#pragma unroll
      for (int i=0;i<4;i++){
#pragma unroll
        for (int j=0;j<4;j++) acc[i][j] += ar[i]*br[j];
      }
    }
  }
#pragma unroll
  for (int i=0;i<4;i++){
    int gm = m0 + (ty<<2) + i;
    float vj[4];
#pragma unroll
    for (int j=0;j<4;j++){
      float v = acc[i][j] + bias[n0+(tx<<2)+j];
      if (ACT==1) v = gelu_f(v);
      vj[j]=v;
    }
    *reinterpret_cast<float4*>(C + (size_t)gm*N + n0 + (tx<<2)) = make_float4(vj[0],vj[1],vj[2],vj[3]);
  }
}

// LayerNorm over D=256 per position (gamma/beta), block=256
__global__ __launch_bounds__(256) void k_ln(const float* __restrict__ x, const float* __restrict__ g,
                                            const float* __restrict__ bta, float* __restrict__ out){
  __shared__ float red[8];
  int m = blockIdx.x, d = threadIdx.x;
  float v = x[(size_t)m*DD + d];
  float s1 = v, s2 = v*v;
  for (int off=32; off; off>>=1){ s1 += __shfl_down(s1,off); s2 += __shfl_down(s2,off); }
  int wid = d >> 6;
  if ((d&63)==0){ red[wid*2]=s1; red[wid*2+1]=s2; }
  __syncthreads();
  float sum = red[0]+red[2]+red[4]+red[6];
  float sq  = red[1]+red[3]+red[5]+red[7];
  float mean = sum * (1.f/DD);
  float var  = sq  * (1.f/DD) - mean*mean;
  float inv  = rsqrtf(fmaxf(var,0.f) + 1e-5f);
  out[(size_t)m*DD + d] = (v-mean)*inv*g[d] + bta[d];
}

// Forward scans: base = seq + tf; lk1 = lnp@base, lk2 = lnp@lk1, lc = lnp@seq.
// Recurrence z[s] = a[s-1]*x[s-1] + (1-a[s-1]+eps)*z[s-1]. Writes ws[m][{0,1,2}][d], lc.
__global__ __launch_bounds__(64) void k_scanF(const float* __restrict__ seq,
    const float* __restrict__ ltp, const float* __restrict__ act,
    const float* __restrict__ yes_t, const float* __restrict__ no_t,
    float* __restrict__ ws, float* __restrict__ lc){
  int b = blockIdx.x;
  int d = blockIdx.y*64 + threadIdx.x;
  float yv = yes_t[d], nv = no_t[d];
  float z1=0.f, z2=0.f, zc=0.f, pb=0.f, ps=0.f, pa=0.f;
  for (int s=0; s<S2; ++s){
    size_t m = (size_t)b*S2 + s;
    float sv = seq[m*DD + d];
    float lt = ltp[m];
    float av = act[m];
    float bse = sv + lt*yv + (1.f-lt)*nv;
    if (s > 0){
      float c = pa, f = 1.f - c + EPSF;
      z2 = c*z1 + f*z2;      // uses lk1[s-1] before its update
      z1 = c*pb + f*z1;
      zc = c*ps + f*zc;
    }
    size_t w5 = m*5*DD;
    ws[w5 + 0*DD + d] = z2;
    ws[w5 + 1*DD + d] = z1;
    ws[w5 + 2*DD + d] = bse;
    lc[m*DD + d] = zc;
    pb = bse; ps = sv; pa = av;
  }
}

// Backward scans: rk1 = rnp@base, rk2 = rnp@rk1. Writes ws[m][{3,4}][d].
__global__ __launch_bounds__(64) void k_scanB(const float* __restrict__ seq,
    const float* __restrict__ ltp, const float* __restrict__ act,
    const float* __restrict__ yes_t, const float* __restrict__ no_t,
    float* __restrict__ ws){
  int b = blockIdx.x;
  int d = blockIdx.y*64 + threadIdx.x;
  float yv = yes_t[d], nv = no_t[d];
  float y1=0.f, y2=0.f, pb=0.f, pa=0.f;
  for (int s=S2-1; s>=0; --s){
    size_t m = (size_t)b*S2 + s;
    float sv = seq[m*DD + d];
    float lt = ltp[m];
    float av = act[m];
    float bse = sv + lt*yv + (1.f-lt)*nv;
    if (s < S2-1){
      float c = pa, f = 1.f - c + EPSF;
      y2 = c*y1 + f*y2;
      y1 = c*pb + f*y1;
    }
    size_t w5 = m*5*DD;
    ws[w5 + 3*DD + d] = y1;
    ws[w5 + 4*DD + d] = y2;
    pb = bse; pa = av;
  }
}

// tsc[m] = dot(h[m,:], scW) + scb
__global__ __launch_bounds__(64) void k_score(const float* __restrict__ h,
    const float* __restrict__ scW, const float* __restrict__ scb, float* __restrict__ tsc){
  int m = blockIdx.x, t = threadIdx.x;
  float s = 0.f;
  for (int d=t; d<DD; d+=64) s += h[(size_t)m*DD+d]*scW[d];
  for (int off=32; off; off>>=1) s += __shfl_down(s, off);
  if (t==0) tsc[m] = s + scb[0];
}

__global__ __launch_bounds__(1024) void k_maxred(const float* __restrict__ tsc, float* __restrict__ mx){
  __shared__ float red[16];
  int t = threadIdx.x;
  float v = 0.f;   // max with 0.0 baked in
  for (int i=t; i<MS; i+=1024) v = fmaxf(v, tsc[i]);
  for (int off=32; off; off>>=1) v = fmaxf(v, __shfl_down(v, off));
  int wid = t>>6;
  if ((t&63)==0) red[wid]=v;
  __syncthreads();
  if (t==0){
    float r = red[0];
    for (int i=1;i<16;i++) r=fmaxf(r,red[i]);
    mx[0]=r;
  }
}

__global__ void k_tp(const float* __restrict__ tsc, const float* __restrict__ mx, float* __restrict__ ltp){
  int m = blockIdx.x*256 + threadIdx.x;
  if (m >= MS) return;
  int s = m % S2;
  float sel = (s >= 1 && s <= SS-1) ? 1.f : 0.f;   // selp: 1 on [1,511]
  float M = mx[0];
  float et = expf(tsc[m]-M)*sel;
  float en = expf(-M);
  ltp[m] = et/(et+en+EPSF);
}

// Gates/parent + LN + gated seq update (in-place per position)
__global__ __launch_bounds__(256) void k_epi(const float* __restrict__ contents,
     const float* __restrict__ lc, const float* __restrict__ tp,
     const float* __restrict__ g, const float* __restrict__ bta,
     float* __restrict__ seq){
  __shared__ float red[8];
  int m = blockIdx.x, d = threadIdx.x;
  size_t b4 = (size_t)m*HH;
  float lcv = lc[(size_t)m*DD+d];
  float sv  = seq[(size_t)m*DD+d];
  float g0 = sigmoid_f(contents[b4 + d]);
  float g1 = sigmoid_f(contents[b4 + DD + d]);
  float g2 = sigmoid_f(contents[b4 + 2*DD + d]);
  float pv = contents[b4 + 3*DD + d];
  float x = g0*lcv + g1*sv + g2*pv;
  float s1=x, s2=x*x;
  for (int off=32; off; off>>=1){ s1 += __shfl_down(s1,off); s2 += __shfl_down(s2,off); }
  int wid = d>>6;
  if ((d&63)==0){ red[wid*2]=s1; red[wid*2+1]=s2; }
  __syncthreads();
  float sum=red[0]+red[2]+red[4]+red[6];
  float sq =red[1]+red[3]+red[5]+red[7];
  float mean = sum*(1.f/DD);
  float var  = sq *(1.f/DD)-mean*mean;
  float inv = rsqrtf(fmaxf(var,0.f)+1e-5f);
  float comp = (x-mean)*inv*g[d] + bta[d];
  float t = tp[m];
  seq[(size_t)m*DD+d] = t*comp + (1.f-t)*sv;
}

// deact[j] = a[j]*u[j]; u[j] = tp[j+1] + (1-a[j+1]+eps)*u[j+1]  (lnp^T @ tp scan);
// active = clip(active*(1-deact),0,1)
__global__ void k_actup(const float* __restrict__ tp, float* __restrict__ act){
  if (threadIdx.x != 0) return;
  int b = blockIdx.x;
  float u = 0.f;
  for (int s=S2-1; s>=0; --s){
    size_t m = (size_t)b*S2+s;
    float a = act[m];
    float na = a*(1.f - a*u);
    na = fminf(fmaxf(na, 0.f), 1.f);
    act[m] = na;
    u = tp[m] + (1.f-a+EPSF)*u;
  }
}

extern "C" void kernel_launch(void* const* d_in, const int* in_sizes, int n_in,
                              void* d_out, int out_size, void* d_ws, size_t ws_size,
                              hipStream_t stream){
  const float* seq_in = (const float*)d_in[0];
  const float* START = (const float*)d_in[2];
  const float* END   = (const float*)d_in[3];
  const float* yes_t = (const float*)d_in[4];
  const float* no_t  = (const float*)d_in[5];
  const float* convW = (const float*)d_in[6];
  const float* convb = (const float*)d_in[7];
  const float* scW   = (const float*)d_in[8];
  const float* scb   = (const float*)d_in[9];
  const float* itW   = (const float*)d_in[10];
  const float* itb   = (const float*)d_in[11];
  const float* w1W   = (const float*)d_in[12];
  const float* w1b   = (const float*)d_in[13];
  const float* w2W   = (const float*)d_in[14];
  const float* w2b   = (const float*)d_in[15];
  const float* lng   = (const float*)d_in[16];
  const float* lnb   = (const float*)d_in[17];

  // Workspace layout (floats). Aliasing: R1 holds ws(5D) then inter; R2 holds h then contents.
  float* ws  = (float*)d_ws;
  float* seq = ws;                 // MD, persistent
  float* lc  = seq + MD;           // MD
  float* R1  = lc + MD;            // MD5 (ws / inter)
  float* R2  = R1 + MD5;           // MH  (seq0-out / h / contents)
  float* ltp = R2 + MH;            // MS  (holds ltp, then tp after k_tp)
  float* act = ltp + MS;           // MS
  float* tsc = act + MS;           // MS
  float* mx  = tsc + MS;           // 1

  dim3 b256(256), b64(64);

  // init: seq0 -> R1; preLN = seq0@itW+itb -> R2; seq = LN(preLN)
  k_build_seq0<<<MS, 256, 0, stream>>>(seq_in, START, END, R1);
  { dim3 g(MS/64, DD/64); k_sgemm<0,false><<<g, b256, 0, stream>>>(R1, nullptr, DD, itW, itb, R2, MS, DD, DD); }
  k_ln<<<MS, 256, 0, stream>>>(R2, lng, lnb, seq);
  k_init_state<<<(MS+255)/256, 256, 0, stream>>>(ltp, act);

  for (int step=0; step<NSTEPS; ++step){
    { dim3 g(NB, DD/64); k_scanF<<<g, b64, 0, stream>>>(seq, ltp, act, yes_t, no_t, R1, lc); }
    { dim3 g(NB, DD/64); k_scanB<<<g, b64, 0, stream>>>(seq, ltp, act, yes_t, no_t, R1); }
    // h = gelu(ws@convW + convb) -> R2
    { dim3 g(MS/64, DD/64); k_sgemm<1,false><<<g, b256, 0, stream>>>(R1, nullptr, 5*DD, convW, convb, R2, MS, DD, 5*DD); }
    k_score<<<MS, 64, 0, stream>>>(R2, scW, scb, tsc);
    k_maxred<<<1, 1024, 0, stream>>>(tsc, mx);
    k_tp<<<(MS+255)/256, 256, 0, stream>>>(tsc, mx, ltp);   // ltp now holds tp
    // inter = gelu([lc|seq]@w1W + w1b) -> R1
    { dim3 g(MS/64, HH/64); k_sgemm<1,true><<<g, b256, 0, stream>>>(lc, seq, DD, w1W, w1b, R1, MS, HH, 2*DD); }
    // contents = inter@w2W + w2b -> R2
    { dim3 g(MS/64, HH/64); k_sgemm<0,false><<<g, b256, 0, stream>>>(R1, nullptr, HH, w2W, w2b, R2, MS, HH, HH); }
    k_epi<<<MS, 256, 0, stream>>>(R2, lc, ltp, lng, lnb, seq);
    k_actup<<<NB, 64, 0, stream>>>(ltp, act);
  }
  hipMemcpyAsync(d_out, seq, (size_t)out_size*sizeof(float), hipMemcpyDeviceToDevice, stream);
}

// Round 2
// 2671.862 us; speedup vs baseline: 2.5046x; 2.5046x over previous
//
#include <hip/hip_runtime.h>
#include <math.h>

#define NB 32
#define SS 512
#define S2 514
#define DD 256
#define HH 1024
#define MS (NB*S2)                     // 16448 real rows
#define MP 16512                       // padded to 129*128 for 128-tile GEMM
#define EPSF 1e-9f
#define NSTEPS 6

typedef unsigned short ushort_t;
typedef __attribute__((ext_vector_type(8))) short short8;
typedef __attribute__((ext_vector_type(4))) float f32x4;

__device__ __forceinline__ float gelu_f(float x){
  float t = tanhf(0.7978845608028654f*(x + 0.044715f*x*x*x));
  return 0.5f*x*(1.f+t);
}
__device__ __forceinline__ float sigmoid_f(float x){ return 1.f/(1.f+expf(-x)); }
__device__ __forceinline__ ushort_t f2bf(float f){
  unsigned u = __float_as_uint(f);
  u += 0x7fffu + ((u>>16)&1u);        // RNE
  return (ushort_t)(u>>16);
}
__device__ __forceinline__ void gload_lds16(const void* g, void* l){
  __builtin_amdgcn_global_load_lds((const __attribute__((address_space(1))) void*)g,
                                   (__attribute__((address_space(3))) void*)l, 16, 0, 0);
}

// ---------------- weight transpose + bf16 convert: WT[n][k] = W[k][n] ----------------
__global__ __launch_bounds__(256) void k_wt(const float* __restrict__ W, ushort_t* __restrict__ WT,
                                            int K, int N){
  __shared__ float t[64][65];
  int k0 = blockIdx.x*64, n0 = blockIdx.y*64;
  int tx = threadIdx.x & 63, ty = threadIdx.x >> 6;
#pragma unroll
  for (int i=ty;i<64;i+=4) t[i][tx] = W[(size_t)(k0+i)*N + n0 + tx];
  __syncthreads();
#pragma unroll
  for (int i=ty;i<64;i+=4) WT[(size_t)(n0+i)*K + k0 + tx] = f2bf(t[tx][i]);
}

// ---------------- build padded seq0 in bf16 ----------------
__global__ void k_build_seq0(const float* __restrict__ seq_in, const float* __restrict__ START,
                             const float* __restrict__ END, ushort_t* __restrict__ out){
  int m = blockIdx.x; int d = threadIdx.x;
  int s = m % S2; int b = m / S2;
  float v;
  if (s == 0)        v = START[d];
  else if (s <= SS)  v = seq_in[((size_t)(b*SS + (s-1)))*DD + d];
  else               v = END[d];
  out[(size_t)m*DD + d] = f2bf(v);
}

__global__ void k_init_state(float* __restrict__ ltp, float* __restrict__ act){
  int i = blockIdx.x*256 + threadIdx.x;
  if (i < MS){ ltp[i]=0.f; act[i]=1.f; }
}

// ---------------- MFMA bf16 GEMM, m97 structure ----------------
// C[M][N] = act(A[M][K] @ BT[N][K]^T + bias). 128x128 tile, BK=32, 4 waves,
// 16x16x32 bf16 MFMA, global_load_lds(16B), 2 barriers per K-step.
template<int ACT, int OUTBF>
__global__ __launch_bounds__(256) void k_mgemm(const ushort_t* __restrict__ A,
    const ushort_t* __restrict__ BT, const float* __restrict__ bias,
    float* __restrict__ Cf, ushort_t* __restrict__ Cb, int M, int N, int K)
{
  __shared__ __align__(16) ushort_t Asm[128*32];   // [row][k]
  __shared__ __align__(16) ushort_t Bsm[128*32];   // [col][k]
  const int tid = threadIdx.x;
  const int lane = tid & 63, wid = tid >> 6;
  const int m0 = blockIdx.x * 128, n0 = blockIdx.y * 128;
  const int wr = (wid>>1)*64, wc = (wid&1)*64;

  f32x4 acc[4][4];
#pragma unroll
  for (int i=0;i<4;i++)
#pragma unroll
    for (int j=0;j<4;j++) acc[i][j] = (f32x4){0.f,0.f,0.f,0.f};

  const int lrow = lane>>2, lk = (lane&3)<<3;       // lane's slot in a 1KB chunk
  const ushort_t* Ag0 = A  + (size_t)(m0 + lrow)*K + lk;
  const ushort_t* Bg0 = BT + (size_t)(n0 + lrow)*K + lk;

  for (int k0=0; k0<K; k0+=32){
    __syncthreads();                                 // prev tile's ds_reads done
#pragma unroll
    for (int c2=0; c2<2; ++c2){
      int c = wid + c2*4;                            // chunks: rows [c*16, c*16+16)
      gload_lds16(Ag0 + (size_t)(c*16)*K + k0, &Asm[c*512]);
      gload_lds16(Bg0 + (size_t)(c*16)*K + k0, &Bsm[c*512]);
    }
    __syncthreads();                                 // vmcnt drained -> LDS ready
    short8 a[4], b[4];
#pragma unroll
    for (int i=0;i<4;i++){
      a[i] = *reinterpret_cast<const short8*>(&Asm[(wr + i*16 + (lane&15))*32 + (lane>>4)*8]);
      b[i] = *reinterpret_cast<const short8*>(&Bsm[(wc + i*16 + (lane&15))*32 + (lane>>4)*8]);
    }
#pragma unroll
    for (int i=0;i<4;i++)
#pragma unroll
      for (int j=0;j<4;j++)
        acc[i][j] = __builtin_amdgcn_mfma_f32_16x16x32_bf16(a[i], b[j], acc[i][j], 0,0,0);
  }
  // epilogue: C/D layout col=lane&15, row=(lane>>4)*4+reg (verified m89)
#pragma unroll
  for (int i=0;i<4;i++){
#pragma unroll
    for (int r=0;r<4;r++){
      size_t gm = m0 + wr + i*16 + (lane>>4)*4 + r;
#pragma unroll
      for (int j=0;j<4;j++){
        int gn = n0 + wc + j*16 + (lane&15);
        float v = acc[i][j][r] + bias[gn];
        if (ACT==1) v = gelu_f(v);
        if (OUTBF) Cb[gm*N + gn] = f2bf(v);
        else       Cf[gm*N + gn] = v;
      }
    }
  }
}

// ---------------- LayerNorm (init): seq=LN(preLN), also bf16 copy into cc[:,256:512] ----
__global__ __launch_bounds__(256) void k_ln(const float* __restrict__ x, const float* __restrict__ g,
                                            const float* __restrict__ bta, float* __restrict__ out,
                                            ushort_t* __restrict__ cc){
  __shared__ float red[8];
  int m = blockIdx.x, d = threadIdx.x;
  float v = x[(size_t)m*DD + d];
  float s1 = v, s2 = v*v;
  for (int off=32; off; off>>=1){ s1 += __shfl_down(s1,off); s2 += __shfl_down(s2,off); }
  int wid = d >> 6;
  if ((d&63)==0){ red[wid*2]=s1; red[wid*2+1]=s2; }
  __syncthreads();
  float sum = red[0]+red[2]+red[4]+red[6];
  float sq  = red[1]+red[3]+red[5]+red[7];
  float mean = sum * (1.f/DD);
  float var  = sq  * (1.f/DD) - mean*mean;
  float inv  = rsqrtf(fmaxf(var,0.f) + 1e-5f);
  float o = (v-mean)*inv*g[d] + bta[d];
  out[(size_t)m*DD + d] = o;
  cc[(size_t)m*(2*DD) + DD + d] = f2bf(o);
}

// ---------------- forward scans -> ws5 slices 0,1,2 (bf16), lc f32 + cc[:,0:256] bf16 ----
__global__ __launch_bounds__(64) void k_scanF(const float* __restrict__ seq,
    const float* __restrict__ ltp, const float* __restrict__ act,
    const float* __restrict__ yes_t, const float* __restrict__ no_t,
    ushort_t* __restrict__ ws5, float* __restrict__ lc, ushort_t* __restrict__ cc){
  int b = blockIdx.x;
  int d = blockIdx.y*64 + threadIdx.x;
  float yv = yes_t[d], nv = no_t[d];
  float z1=0.f, z2=0.f, zc=0.f, pb=0.f, ps=0.f, pa=0.f;
  for (int s=0; s<S2; ++s){
    size_t m = (size_t)b*S2 + s;
    float sv = seq[m*DD + d];
    float lt = ltp[m];
    float av = act[m];
    float bse = sv + lt*yv + (1.f-lt)*nv;
    if (s > 0){
      float c = pa, f = 1.f - c + EPSF;
      z2 = c*z1 + f*z2;
      z1 = c*pb + f*z1;
      zc = c*ps + f*zc;
    }
    size_t w5 = m*(5*DD);
    ws5[w5 + 0*DD + d] = f2bf(z2);
    ws5[w5 + 1*DD + d] = f2bf(z1);
    ws5[w5 + 2*DD + d] = f2bf(bse);
    lc[m*DD + d] = zc;
    cc[m*(2*DD) + d] = f2bf(zc);
    pb = bse; ps = sv; pa = av;
  }
}

// ---------------- backward scans -> ws5 slices 3,4 (bf16) ----------------
__global__ __launch_bounds__(64) void k_scanB(const float* __restrict__ seq,
    const float* __restrict__ ltp, const float* __restrict__ act,
    const float* __restrict__ yes_t, const float* __restrict__ no_t,
    ushort_t* __restrict__ ws5){
  int b = blockIdx.x;
  int d = blockIdx.y*64 + threadIdx.x;
  float yv = yes_t[d], nv = no_t[d];
  float y1=0.f, y2=0.f, pb=0.f, pa=0.f;
  for (int s=S2-1; s>=0; --s){
    size_t m = (size_t)b*S2 + s;
    float sv = seq[m*DD + d];
    float lt = ltp[m];
    float av = act[m];
    float bse = sv + lt*yv + (1.f-lt)*nv;
    if (s < S2-1){
      float c = pa, f = 1.f - c + EPSF;
      y2 = c*y1 + f*y2;
      y1 = c*pb + f*y1;
    }
    size_t w5 = m*(5*DD);
    ws5[w5 + 3*DD + d] = f2bf(y1);
    ws5[w5 + 4*DD + d] = f2bf(y2);
    pb = bse; pa = av;
  }
}

// ---------------- tsc[m] = dot(h[m,:], scW) + scb ----------------
__global__ __launch_bounds__(64) void k_score(const float* __restrict__ h,
    const float* __restrict__ scW, const float* __restrict__ scb, float* __restrict__ tsc){
  int m = blockIdx.x, t = threadIdx.x;
  float s = 0.f;
  for (int d=t; d<DD; d+=64) s += h[(size_t)m*DD+d]*scW[d];
  for (int off=32; off; off>>=1) s += __shfl_down(s, off);
  if (t==0) tsc[m] = s + scb[0];
}

__global__ __launch_bounds__(1024) void k_maxred(const float* __restrict__ tsc, float* __restrict__ mx){
  __shared__ float red[16];
  int t = threadIdx.x;
  float v = 0.f;
  for (int i=t; i<MS; i+=1024) v = fmaxf(v, tsc[i]);
  for (int off=32; off; off>>=1) v = fmaxf(v, __shfl_down(v, off));
  int wid = t>>6;
  if ((t&63)==0) red[wid]=v;
  __syncthreads();
  if (t==0){
    float r = red[0];
    for (int i=1;i<16;i++) r=fmaxf(r,red[i]);
    mx[0]=r;
  }
}

__global__ void k_tp(const float* __restrict__ tsc, const float* __restrict__ mx, float* __restrict__ ltp){
  int m = blockIdx.x*256 + threadIdx.x;
  if (m >= MS) return;
  int s = m % S2;
  float sel = (s >= 1 && s <= SS-1) ? 1.f : 0.f;
  float M = mx[0];
  float et = expf(tsc[m]-M)*sel;
  float en = expf(-M);
  ltp[m] = et/(et+en+EPSF);
}

// ---------------- gates + LN + gated update; writes seq f32 + cc bf16 ----------------
__global__ __launch_bounds__(256) void k_epi(const float* __restrict__ contents,
     const float* __restrict__ lc, const float* __restrict__ tp,
     const float* __restrict__ g, const float* __restrict__ bta,
     float* __restrict__ seq, ushort_t* __restrict__ cc){
  __shared__ float red[8];
  int m = blockIdx.x, d = threadIdx.x;
  size_t b4 = (size_t)m*HH;
  float lcv = lc[(size_t)m*DD+d];
  float sv  = seq[(size_t)m*DD+d];
  float g0 = sigmoid_f(contents[b4 + d]);
  float g1 = sigmoid_f(contents[b4 + DD + d]);
  float g2 = sigmoid_f(contents[b4 + 2*DD + d]);
  float pv = contents[b4 + 3*DD + d];
  float x = g0*lcv + g1*sv + g2*pv;
  float s1=x, s2=x*x;
  for (int off=32; off; off>>=1){ s1 += __shfl_down(s1,off); s2 += __shfl_down(s2,off); }
  int wid = d>>6;
  if ((d&63)==0){ red[wid*2]=s1; red[wid*2+1]=s2; }
  __syncthreads();
  float sum=red[0]+red[2]+red[4]+red[6];
  float sq =red[1]+red[3]+red[5]+red[7];
  float mean = sum*(1.f/DD);
  float var  = sq *(1.f/DD)-mean*mean;
  float inv = rsqrtf(fmaxf(var,0.f)+1e-5f);
  float comp = (x-mean)*inv*g[d] + bta[d];
  float t = tp[m];
  float o = t*comp + (1.f-t)*sv;
  seq[(size_t)m*DD+d] = o;
  cc[(size_t)m*(2*DD) + DD + d] = f2bf(o);
}

// ---------------- active update: LDS-staged serial scan per batch ----------------
__global__ __launch_bounds__(64) void k_actup(const float* __restrict__ tp, float* __restrict__ act){
  __shared__ float sa[S2], st[S2];
  int b = blockIdx.x, t = threadIdx.x;
  for (int s=t; s<S2; s+=64){ sa[s]=act[(size_t)b*S2+s]; st[s]=tp[(size_t)b*S2+s]; }
  __syncthreads();
  if (t==0){
    float u = 0.f;
    for (int s=S2-1; s>=0; --s){
      float a = sa[s];
      float na = a*(1.f - a*u);
      sa[s] = fminf(fmaxf(na, 0.f), 1.f);
      u = st[s] + (1.f-a+EPSF)*u;
    }
  }
  __syncthreads();
  for (int s=t; s<S2; s+=64) act[(size_t)b*S2+s]=sa[s];
}

extern "C" void kernel_launch(void* const* d_in, const int* in_sizes, int n_in,
                              void* d_out, int out_size, void* d_ws, size_t ws_size,
                              hipStream_t stream){
  const float* seq_in = (const float*)d_in[0];
  const float* START = (const float*)d_in[2];
  const float* END   = (const float*)d_in[3];
  const float* yes_t = (const float*)d_in[4];
  const float* no_t  = (const float*)d_in[5];
  const float* convW = (const float*)d_in[6];
  const float* convb = (const float*)d_in[7];
  const float* scW   = (const float*)d_in[8];
  const float* scb   = (const float*)d_in[9];
  const float* itW   = (const float*)d_in[10];
  const float* itb   = (const float*)d_in[11];
  const float* w1W   = (const float*)d_in[12];
  const float* w1b   = (const float*)d_in[13];
  const float* w2W   = (const float*)d_in[14];
  const float* w2b   = (const float*)d_in[15];
  const float* lng   = (const float*)d_in[16];
  const float* lnb   = (const float*)d_in[17];

  // ---- workspace layout (all regions 256B-aligned by construction) ----
  char* p = (char*)d_ws;
  float*    seq  = (float*)p;    p += (size_t)MP*DD*4;          // f32 state
  float*    lc   = (float*)p;    p += (size_t)MP*DD*4;          // f32 left_child
  ushort_t* cc   = (ushort_t*)p; p += (size_t)MP*(2*DD)*2;      // bf16 [lc|seq]
  // region A: ws5 bf16 (MP*1280*2=MP*2560B) / contents f32 (MP*4096B) / preLN f32 (MP*1024B)
  ushort_t* ws5      = (ushort_t*)p;
  float*    contents = (float*)p;
  float*    preLN    = (float*)p; p += (size_t)MP*4096;
  // region B: h f32 (MP*1024B) / inter bf16 (MP*2048B) / seq0 bf16 (MP*512B)
  float*    h     = (float*)p;
  ushort_t* inter = (ushort_t*)p;
  ushort_t* seq0  = (ushort_t*)p; p += (size_t)MP*2048;
  ushort_t* itWT   = (ushort_t*)p; p += (size_t)256*256*2;
  ushort_t* convWT = (ushort_t*)p; p += (size_t)256*1280*2;
  ushort_t* w1WT   = (ushort_t*)p; p += (size_t)1024*512*2;
  ushort_t* w2WT   = (ushort_t*)p; p += (size_t)1024*1024*2;
  float* ltp = (float*)p; p += (size_t)MS*4;
  float* act = (float*)p; p += (size_t)MS*4;
  float* tsc = (float*)p; p += (size_t)MS*4;
  float* mx  = (float*)p; p += 256;

  dim3 b256(256), b64(64);

  // weights -> bf16 transposed (once per launch; same work every call)
  { dim3 g(256/64, 256/64);   k_wt<<<g, b256, 0, stream>>>(itW,  itWT,  256, 256); }
  { dim3 g(1280/64, 256/64);  k_wt<<<g, b256, 0, stream>>>(convW,convWT,1280,256); }
  { dim3 g(512/64, 1024/64);  k_wt<<<g, b256, 0, stream>>>(w1W,  w1WT,  512, 1024); }
  { dim3 g(1024/64, 1024/64); k_wt<<<g, b256, 0, stream>>>(w2W,  w2WT,  1024,1024); }

  // init: seq0(bf16) -> preLN = seq0@itW+itb -> seq = LN(preLN)
  k_build_seq0<<<MS, 256, 0, stream>>>(seq_in, START, END, seq0);
  { dim3 g(MP/128, 256/128); k_mgemm<0,0><<<g, b256, 0, stream>>>(seq0, itWT, itb, preLN, nullptr, MP, 256, 256); }
  k_ln<<<MS, 256, 0, stream>>>(preLN, lng, lnb, seq, cc);
  k_init_state<<<(MS+255)/256, 256, 0, stream>>>(ltp, act);

  for (int step=0; step<NSTEPS; ++step){
    { dim3 g(NB, DD/64); k_scanF<<<g, b64, 0, stream>>>(seq, ltp, act, yes_t, no_t, ws5, lc, cc); }
    { dim3 g(NB, DD/64); k_scanB<<<g, b64, 0, stream>>>(seq, ltp, act, yes_t, no_t, ws5); }
    // h = gelu(ws5@convW + convb)   [M,256] f32
    { dim3 g(MP/128, 256/128); k_mgemm<1,0><<<g, b256, 0, stream>>>(ws5, convWT, convb, h, nullptr, MP, 256, 5*DD); }
    k_score<<<MS, 64, 0, stream>>>(h, scW, scb, tsc);
    k_maxred<<<1, 1024, 0, stream>>>(tsc, mx);
    k_tp<<<(MS+255)/256, 256, 0, stream>>>(tsc, mx, ltp);     // ltp now holds tp
    // inter = gelu(cc@w1W + w1b)    [M,1024] bf16
    { dim3 g(MP/128, HH/128); k_mgemm<1,1><<<g, b256, 0, stream>>>(cc, w1WT, w1b, nullptr, inter, MP, HH, 2*DD); }
    // contents = inter@w2W + w2b    [M,1024] f32
    { dim3 g(MP/128, HH/128); k_mgemm<0,0><<<g, b256, 0, stream>>>(inter, w2WT, w2b, contents, nullptr, MP, HH, HH); }
    k_epi<<<MS, 256, 0, stream>>>(contents, lc, ltp, lng, lnb, seq, cc);
    k_actup<<<NB, b64, 0, stream>>>(ltp, act);
  }
  hipMemcpyAsync(d_out, seq, (size_t)out_size*sizeof(float), hipMemcpyDeviceToDevice, stream);
}

// Round 3
// 1835.721 us; speedup vs baseline: 3.6454x; 1.4555x over previous
//
#include <hip/hip_runtime.h>
#include <math.h>

#define NB 32
#define SS 512
#define S2 514
#define DD 256
#define HH 1024
#define MS (NB*S2)                     // 16448 real rows
#define MP 16512                       // padded to 129*128 for 128-tile GEMM
#define EPSF 1e-9f
#define NSTEPS 6
#define CHK 64

typedef unsigned short ushort_t;
typedef __attribute__((ext_vector_type(8))) short short8;
typedef __attribute__((ext_vector_type(4))) float f32x4;

__device__ __forceinline__ float gelu_f(float x){
  float t = tanhf(0.7978845608028654f*(x + 0.044715f*x*x*x));
  return 0.5f*x*(1.f+t);
}
__device__ __forceinline__ float sigmoid_f(float x){ return 1.f/(1.f+expf(-x)); }
__device__ __forceinline__ ushort_t f2bf(float f){
  unsigned u = __float_as_uint(f);
  u += 0x7fffu + ((u>>16)&1u);        // RNE
  return (ushort_t)(u>>16);
}
__device__ __forceinline__ void gload_lds16(const void* g, void* l){
  __builtin_amdgcn_global_load_lds((const __attribute__((address_space(1))) void*)g,
                                   (__attribute__((address_space(3))) void*)l, 16, 0, 0);
}

// ---------------- weight transpose + bf16 convert: WT[n][k] = W[k][n] ----------------
__global__ __launch_bounds__(256) void k_wt(const float* __restrict__ W, ushort_t* __restrict__ WT,
                                            int K, int N){
  __shared__ float t[64][65];
  int k0 = blockIdx.x*64, n0 = blockIdx.y*64;
  int tx = threadIdx.x & 63, ty = threadIdx.x >> 6;
#pragma unroll
  for (int i=ty;i<64;i+=4) t[i][tx] = W[(size_t)(k0+i)*N + n0 + tx];
  __syncthreads();
#pragma unroll
  for (int i=ty;i<64;i+=4) WT[(size_t)(n0+i)*K + k0 + tx] = f2bf(t[tx][i]);
}

// ---------------- build padded seq0 in bf16 ----------------
__global__ void k_build_seq0(const float* __restrict__ seq_in, const float* __restrict__ START,
                             const float* __restrict__ END, ushort_t* __restrict__ out){
  int m = blockIdx.x; int d = threadIdx.x;
  int s = m % S2; int b = m / S2;
  float v;
  if (s == 0)        v = START[d];
  else if (s <= SS)  v = seq_in[((size_t)(b*SS + (s-1)))*DD + d];
  else               v = END[d];
  out[(size_t)m*DD + d] = f2bf(v);
}

__global__ void k_init_state(float* __restrict__ ltp, float* __restrict__ act){
  int i = blockIdx.x*256 + threadIdx.x;
  if (i < MS){ ltp[i]=0.f; act[i]=1.f; }
}

// ---------------- MFMA bf16 GEMM, m97 structure ----------------
template<int ACT, int OUTBF>
__global__ __launch_bounds__(256) void k_mgemm(const ushort_t* __restrict__ A,
    const ushort_t* __restrict__ BT, const float* __restrict__ bias,
    float* __restrict__ Cf, ushort_t* __restrict__ Cb, int M, int N, int K)
{
  __shared__ __align__(16) ushort_t Asm[128*32];   // [row][k]
  __shared__ __align__(16) ushort_t Bsm[128*32];   // [col][k]
  const int tid = threadIdx.x;
  const int lane = tid & 63, wid = tid >> 6;
  const int m0 = blockIdx.x * 128, n0 = blockIdx.y * 128;
  const int wr = (wid>>1)*64, wc = (wid&1)*64;

  f32x4 acc[4][4];
#pragma unroll
  for (int i=0;i<4;i++)
#pragma unroll
    for (int j=0;j<4;j++) acc[i][j] = (f32x4){0.f,0.f,0.f,0.f};

  const int lrow = lane>>2, lk = (lane&3)<<3;
  const ushort_t* Ag0 = A  + (size_t)(m0 + lrow)*K + lk;
  const ushort_t* Bg0 = BT + (size_t)(n0 + lrow)*K + lk;

  for (int k0=0; k0<K; k0+=32){
    __syncthreads();
#pragma unroll
    for (int c2=0; c2<2; ++c2){
      int c = wid + c2*4;
      gload_lds16(Ag0 + (size_t)(c*16)*K + k0, &Asm[c*512]);
      gload_lds16(Bg0 + (size_t)(c*16)*K + k0, &Bsm[c*512]);
    }
    __syncthreads();
    short8 a[4], b[4];
#pragma unroll
    for (int i=0;i<4;i++){
      a[i] = *reinterpret_cast<const short8*>(&Asm[(wr + i*16 + (lane&15))*32 + (lane>>4)*8]);
      b[i] = *reinterpret_cast<const short8*>(&Bsm[(wc + i*16 + (lane&15))*32 + (lane>>4)*8]);
    }
#pragma unroll
    for (int i=0;i<4;i++)
#pragma unroll
      for (int j=0;j<4;j++)
        acc[i][j] = __builtin_amdgcn_mfma_f32_16x16x32_bf16(a[i], b[j], acc[i][j], 0,0,0);
  }
#pragma unroll
  for (int i=0;i<4;i++){
#pragma unroll
    for (int r=0;r<4;r++){
      size_t gm = m0 + wr + i*16 + (lane>>4)*4 + r;
#pragma unroll
      for (int j=0;j<4;j++){
        int gn = n0 + wc + j*16 + (lane&15);
        float v = acc[i][j][r] + bias[gn];
        if (ACT==1) v = gelu_f(v);
        if (OUTBF) Cb[gm*N + gn] = f2bf(v);
        else       Cf[gm*N + gn] = v;
      }
    }
  }
}

// ---------------- LayerNorm (init) ----------------
__global__ __launch_bounds__(256) void k_ln(const float* __restrict__ x, const float* __restrict__ g,
                                            const float* __restrict__ bta, float* __restrict__ out,
                                            ushort_t* __restrict__ cc){
  __shared__ float red[8];
  int m = blockIdx.x, d = threadIdx.x;
  float v = x[(size_t)m*DD + d];
  float s1 = v, s2 = v*v;
  for (int off=32; off; off>>=1){ s1 += __shfl_down(s1,off); s2 += __shfl_down(s2,off); }
  int wid = d >> 6;
  if ((d&63)==0){ red[wid*2]=s1; red[wid*2+1]=s2; }
  __syncthreads();
  float sum = red[0]+red[2]+red[4]+red[6];
  float sq  = red[1]+red[3]+red[5]+red[7];
  float mean = sum * (1.f/DD);
  float var  = sq  * (1.f/DD) - mean*mean;
  float inv  = rsqrtf(fmaxf(var,0.f) + 1e-5f);
  float o = (v-mean)*inv*g[d] + bta[d];
  out[(size_t)m*DD + d] = o;
  cc[(size_t)m*(2*DD) + DD + d] = f2bf(o);
}

// ---------------- fused forward+backward scans, LDS-staged, reg-prefetched ----------------
// grid (NB, 4, 2): batch x 64-dim-group x direction. 64 threads (single wave).
// dir 0: z1=scanF(bse), z2=scanF(z1), zc=scanF(seq) -> ws5 slices {1,0-as-z2? see stores}, lc, cc
// dir 1: y1=scanB(bse), y2=scanB(y1) -> ws5 slices {3,4}
__device__ __forceinline__ void chunk_range(int dir, int ci, int& st, int& ln){
  if (dir==0){ st = ci*CHK; int rem = S2 - st; ln = rem < CHK ? rem : CHK; }
  else { int e = S2 - ci*CHK; st = e - CHK; if (st < 0) st = 0; ln = e - st; }
}

__global__ __launch_bounds__(64) void k_scan(const float* __restrict__ seqp,
    const float* __restrict__ ltpp, const float* __restrict__ actp,
    const float* __restrict__ yes_t, const float* __restrict__ no_t,
    ushort_t* __restrict__ ws5, float* __restrict__ lcp, ushort_t* __restrict__ ccp)
{
  __shared__ float s_seq[2][CHK][64];
  __shared__ float s_sc[2][2][CHK];
  const int b = blockIdx.x, dg = blockIdx.y, dir = blockIdx.z, t = threadIdx.x;
  const int d = (dg<<6) + t;
  const float yv = yes_t[d], nv = no_t[d];
  const int nch = (S2 + CHK - 1)/CHK;   // 9

  float4 rv[16]; float rl, ra;

  int st, ln;
  chunk_range(dir, 0, st, ln);
  // prologue: load + commit chunk 0
#pragma unroll
  for (int r=0;r<16;r++){
    int j = t + (r<<6); int sl = j>>4; int d4 = (j&15)<<2;
    int srow = st + sl; if (srow > S2-1) srow = S2-1;
    rv[r] = *reinterpret_cast<const float4*>(&seqp[((size_t)b*S2+srow)*DD + (dg<<6) + d4]);
  }
  { int srow = st + t; if (srow > S2-1) srow = S2-1;
    rl = ltpp[(size_t)b*S2+srow]; ra = actp[(size_t)b*S2+srow]; }
#pragma unroll
  for (int r=0;r<16;r++){
    int j = t + (r<<6); int sl=j>>4; int d4=(j&15)<<2;
    *reinterpret_cast<float4*>(&s_seq[0][sl][d4]) = rv[r];
  }
  s_sc[0][0][t]=rl; s_sc[0][1][t]=ra;
  __syncthreads();

  float z1=0.f, z2=0.f, zc=0.f, pb=0.f, ps=0.f, pa=0.f;
  int buf = 0;
  for (int ci=0; ci<nch; ++ci){
    int nst=0, nln=0;
    if (ci+1 < nch){
      chunk_range(dir, ci+1, nst, nln);
#pragma unroll
      for (int r=0;r<16;r++){
        int j = t + (r<<6); int sl=j>>4; int d4=(j&15)<<2;
        int srow = nst + sl; if (srow > S2-1) srow = S2-1;
        rv[r] = *reinterpret_cast<const float4*>(&seqp[((size_t)b*S2+srow)*DD + (dg<<6) + d4]);
      }
      int srow = nst + t; if (srow > S2-1) srow = S2-1;
      rl = ltpp[(size_t)b*S2+srow]; ra = actp[(size_t)b*S2+srow];
    }
    // ---- serial scan over current chunk (loads prefetched above stay in flight) ----
    if (dir == 0){
      for (int i=0;i<ln;i++){
        float sv = s_seq[buf][i][t];
        float lt = s_sc[buf][0][i];
        float av = s_sc[buf][1][i];
        float bse = sv + lt*yv + (1.f-lt)*nv;
        float c = pa, f = 1.f - c + EPSF;
        z2 = c*z1 + f*z2;          // lk2 uses lk1[s-1]
        z1 = c*pb + f*z1;
        zc = c*ps + f*zc;
        size_t m = (size_t)b*S2 + st + i;
        size_t w5 = m*(5*DD);
        ws5[w5 + d]        = f2bf(z2);
        ws5[w5 + DD + d]   = f2bf(z1);
        ws5[w5 + 2*DD + d] = f2bf(bse);
        lcp[m*DD + d] = zc;
        ccp[m*(2*DD) + d] = f2bf(zc);
        pb=bse; ps=sv; pa=av;
      }
    } else {
      for (int i=ln-1;i>=0;i--){
        float sv = s_seq[buf][i][t];
        float lt = s_sc[buf][0][i];
        float av = s_sc[buf][1][i];
        float bse = sv + lt*yv + (1.f-lt)*nv;
        float c = pa, f = 1.f - c + EPSF;
        z2 = c*z1 + f*z2;          // rk2 uses rk1[s+1]
        z1 = c*pb + f*z1;
        size_t m = (size_t)b*S2 + st + i;
        size_t w5 = m*(5*DD);
        ws5[w5 + 3*DD + d] = f2bf(z1);
        ws5[w5 + 4*DD + d] = f2bf(z2);
        pb=bse; pa=av;
      }
    }
    if (ci+1 < nch){
#pragma unroll
      for (int r=0;r<16;r++){
        int j = t + (r<<6); int sl=j>>4; int d4=(j&15)<<2;
        *reinterpret_cast<float4*>(&s_seq[buf^1][sl][d4]) = rv[r];
      }
      s_sc[buf^1][0][t]=rl; s_sc[buf^1][1][t]=ra;
      st = nst; ln = nln;
    }
    __syncthreads();
    buf ^= 1;
  }
}

// ---------------- tsc[m] = dot(h[m,:], scW) + scb (float4) ----------------
__global__ __launch_bounds__(64) void k_score(const float* __restrict__ h,
    const float* __restrict__ scW, const float* __restrict__ scb, float* __restrict__ tsc){
  int m = blockIdx.x, t = threadIdx.x;
  float4 hv = *reinterpret_cast<const float4*>(&h[(size_t)m*DD + t*4]);
  float4 wv = *reinterpret_cast<const float4*>(&scW[t*4]);
  float s = hv.x*wv.x + hv.y*wv.y + hv.z*wv.z + hv.w*wv.w;
  for (int off=32; off; off>>=1) s += __shfl_down(s, off);
  if (t==0) tsc[m] = s + scb[0];
}

__global__ __launch_bounds__(1024) void k_maxred(const float* __restrict__ tsc, float* __restrict__ mx){
  __shared__ float red[16];
  int t = threadIdx.x;
  float v = 0.f;
  for (int i=t; i<MS; i+=1024) v = fmaxf(v, tsc[i]);
  for (int off=32; off; off>>=1) v = fmaxf(v, __shfl_down(v, off));
  int wid = t>>6;
  if ((t&63)==0) red[wid]=v;
  __syncthreads();
  if (t==0){
    float r = red[0];
    for (int i=1;i<16;i++) r=fmaxf(r,red[i]);
    mx[0]=r;
  }
}

__global__ void k_tp(const float* __restrict__ tsc, const float* __restrict__ mx, float* __restrict__ ltp){
  int m = blockIdx.x*256 + threadIdx.x;
  if (m >= MS) return;
  int s = m % S2;
  float sel = (s >= 1 && s <= SS-1) ? 1.f : 0.f;
  float M = mx[0];
  float et = expf(tsc[m]-M)*sel;
  float en = expf(-M);
  ltp[m] = et/(et+en+EPSF);
}

// ---------------- gates + LN + gated update ----------------
__global__ __launch_bounds__(256) void k_epi(const float* __restrict__ contents,
     const float* __restrict__ lc, const float* __restrict__ tp,
     const float* __restrict__ g, const float* __restrict__ bta,
     float* __restrict__ seq, ushort_t* __restrict__ cc){
  __shared__ float red[8];
  int m = blockIdx.x, d = threadIdx.x;
  size_t b4 = (size_t)m*HH;
  float lcv = lc[(size_t)m*DD+d];
  float sv  = seq[(size_t)m*DD+d];
  float g0 = sigmoid_f(contents[b4 + d]);
  float g1 = sigmoid_f(contents[b4 + DD + d]);
  float g2 = sigmoid_f(contents[b4 + 2*DD + d]);
  float pv = contents[b4 + 3*DD + d];
  float x = g0*lcv + g1*sv + g2*pv;
  float s1=x, s2=x*x;
  for (int off=32; off; off>>=1){ s1 += __shfl_down(s1,off); s2 += __shfl_down(s2,off); }
  int wid = d>>6;
  if ((d&63)==0){ red[wid*2]=s1; red[wid*2+1]=s2; }
  __syncthreads();
  float sum=red[0]+red[2]+red[4]+red[6];
  float sq =red[1]+red[3]+red[5]+red[7];
  float mean = sum*(1.f/DD);
  float var  = sq *(1.f/DD)-mean*mean;
  float inv = rsqrtf(fmaxf(var,0.f)+1e-5f);
  float comp = (x-mean)*inv*g[d] + bta[d];
  float t = tp[m];
  float o = t*comp + (1.f-t)*sv;
  seq[(size_t)m*DD+d] = o;
  cc[(size_t)m*(2*DD) + DD + d] = f2bf(o);
}

// ---------------- active update ----------------
__global__ __launch_bounds__(64) void k_actup(const float* __restrict__ tp, float* __restrict__ act){
  __shared__ float sa[S2], st_[S2];
  int b = blockIdx.x, t = threadIdx.x;
  for (int s=t; s<S2; s+=64){ sa[s]=act[(size_t)b*S2+s]; st_[s]=tp[(size_t)b*S2+s]; }
  __syncthreads();
  if (t==0){
    float u = 0.f;
    for (int s=S2-1; s>=0; --s){
      float a = sa[s];
      float na = a*(1.f - a*u);
      sa[s] = fminf(fmaxf(na, 0.f), 1.f);
      u = st_[s] + (1.f-a+EPSF)*u;
    }
  }
  __syncthreads();
  for (int s=t; s<S2; s+=64) act[(size_t)b*S2+s]=sa[s];
}

extern "C" void kernel_launch(void* const* d_in, const int* in_sizes, int n_in,
                              void* d_out, int out_size, void* d_ws, size_t ws_size,
                              hipStream_t stream){
  const float* seq_in = (const float*)d_in[0];
  const float* START = (const float*)d_in[2];
  const float* END   = (const float*)d_in[3];
  const float* yes_t = (const float*)d_in[4];
  const float* no_t  = (const float*)d_in[5];
  const float* convW = (const float*)d_in[6];
  const float* convb = (const float*)d_in[7];
  const float* scW   = (const float*)d_in[8];
  const float* scb   = (const float*)d_in[9];
  const float* itW   = (const float*)d_in[10];
  const float* itb   = (const float*)d_in[11];
  const float* w1W   = (const float*)d_in[12];
  const float* w1b   = (const float*)d_in[13];
  const float* w2W   = (const float*)d_in[14];
  const float* w2b   = (const float*)d_in[15];
  const float* lng   = (const float*)d_in[16];
  const float* lnb   = (const float*)d_in[17];

  char* p = (char*)d_ws;
  float*    seq  = (float*)p;    p += (size_t)MP*DD*4;
  float*    lc   = (float*)p;    p += (size_t)MP*DD*4;
  ushort_t* cc   = (ushort_t*)p; p += (size_t)MP*(2*DD)*2;
  ushort_t* ws5      = (ushort_t*)p;
  float*    contents = (float*)p;
  float*    preLN    = (float*)p; p += (size_t)MP*4096;
  float*    h     = (float*)p;
  ushort_t* inter = (ushort_t*)p;
  ushort_t* seq0  = (ushort_t*)p; p += (size_t)MP*2048;
  ushort_t* itWT   = (ushort_t*)p; p += (size_t)256*256*2;
  ushort_t* convWT = (ushort_t*)p; p += (size_t)256*1280*2;
  ushort_t* w1WT   = (ushort_t*)p; p += (size_t)1024*512*2;
  ushort_t* w2WT   = (ushort_t*)p; p += (size_t)1024*1024*2;
  float* ltp = (float*)p; p += (size_t)MS*4;
  float* act = (float*)p; p += (size_t)MS*4;
  float* tsc = (float*)p; p += (size_t)MS*4;
  float* mx  = (float*)p; p += 256;

  dim3 b256(256), b64(64);

  { dim3 g(256/64, 256/64);   k_wt<<<g, b256, 0, stream>>>(itW,  itWT,  256, 256); }
  { dim3 g(1280/64, 256/64);  k_wt<<<g, b256, 0, stream>>>(convW,convWT,1280,256); }
  { dim3 g(512/64, 1024/64);  k_wt<<<g, b256, 0, stream>>>(w1W,  w1WT,  512, 1024); }
  { dim3 g(1024/64, 1024/64); k_wt<<<g, b256, 0, stream>>>(w2W,  w2WT,  1024,1024); }

  k_build_seq0<<<MS, 256, 0, stream>>>(seq_in, START, END, seq0);
  { dim3 g(MP/128, 256/128); k_mgemm<0,0><<<g, b256, 0, stream>>>(seq0, itWT, itb, preLN, nullptr, MP, 256, 256); }
  k_ln<<<MS, 256, 0, stream>>>(preLN, lng, lnb, seq, cc);
  k_init_state<<<(MS+255)/256, 256, 0, stream>>>(ltp, act);

  for (int step=0; step<NSTEPS; ++step){
    { dim3 g(NB, 4, 2); k_scan<<<g, b64, 0, stream>>>(seq, ltp, act, yes_t, no_t, ws5, lc, cc); }
    { dim3 g(MP/128, 256/128); k_mgemm<1,0><<<g, b256, 0, stream>>>(ws5, convWT, convb, h, nullptr, MP, 256, 5*DD); }
    k_score<<<MS, 64, 0, stream>>>(h, scW, scb, tsc);
    k_maxred<<<1, 1024, 0, stream>>>(tsc, mx);
    k_tp<<<(MS+255)/256, 256, 0, stream>>>(tsc, mx, ltp);
    { dim3 g(MP/128, HH/128); k_mgemm<1,1><<<g, b256, 0, stream>>>(cc, w1WT, w1b, nullptr, inter, MP, HH, 2*DD); }
    { dim3 g(MP/128, HH/128); k_mgemm<0,0><<<g, b256, 0, stream>>>(inter, w2WT, w2b, contents, nullptr, MP, HH, HH); }
    k_epi<<<MS, 256, 0, stream>>>(contents, lc, ltp, lng, lnb, seq, cc);
    k_actup<<<NB, b64, 0, stream>>>(ltp, act);
  }
  hipMemcpyAsync(d_out, seq, (size_t)out_size*sizeof(float), hipMemcpyDeviceToDevice, stream);
}

// Round 4
// 1737.487 us; speedup vs baseline: 3.8515x; 1.0565x over previous
//
#include <hip/hip_runtime.h>
#include <math.h>

#define NB 32
#define SS 512
#define S2 514
#define DD 256
#define HH 1024
#define MS (NB*S2)                     // 16448 real rows
#define MP 16512                       // padded to 129*128 for 128-tile GEMM
#define EPSF 1e-9f
#define NSTEPS 6
#define CHK 64

typedef unsigned short ushort_t;
typedef __attribute__((ext_vector_type(8))) short short8;
typedef __attribute__((ext_vector_type(4))) float f32x4;

__device__ __forceinline__ float gelu_f(float x){
  float t = tanhf(0.7978845608028654f*(x + 0.044715f*x*x*x));
  return 0.5f*x*(1.f+t);
}
__device__ __forceinline__ float sigmoid_f(float x){ return 1.f/(1.f+expf(-x)); }
__device__ __forceinline__ ushort_t f2bf(float f){
  unsigned u = __float_as_uint(f);
  u += 0x7fffu + ((u>>16)&1u);        // RNE
  return (ushort_t)(u>>16);
}
__device__ __forceinline__ float bf2f(ushort_t b){
  return __uint_as_float(((unsigned)b)<<16);
}
__device__ __forceinline__ void gload_lds16(const void* g, void* l){
  __builtin_amdgcn_global_load_lds((const __attribute__((address_space(1))) void*)g,
                                   (__attribute__((address_space(3))) void*)l, 16, 0, 0);
}

// ---------------- weight transpose + bf16 convert: WT[n][k] = W[k][n] ----------------
__global__ __launch_bounds__(256) void k_wt(const float* __restrict__ W, ushort_t* __restrict__ WT,
                                            int K, int N){
  __shared__ float t[64][65];
  int k0 = blockIdx.x*64, n0 = blockIdx.y*64;
  int tx = threadIdx.x & 63, ty = threadIdx.x >> 6;
#pragma unroll
  for (int i=ty;i<64;i+=4) t[i][tx] = W[(size_t)(k0+i)*N + n0 + tx];
  __syncthreads();
#pragma unroll
  for (int i=ty;i<64;i+=4) WT[(size_t)(n0+i)*K + k0 + tx] = f2bf(t[tx][i]);
}

// ---------------- build padded seq0 in bf16 ----------------
__global__ void k_build_seq0(const float* __restrict__ seq_in, const float* __restrict__ START,
                             const float* __restrict__ END, ushort_t* __restrict__ out){
  int m = blockIdx.x; int d = threadIdx.x;
  int s = m % S2; int b = m / S2;
  float v;
  if (s == 0)        v = START[d];
  else if (s <= SS)  v = seq_in[((size_t)(b*SS + (s-1)))*DD + d];
  else               v = END[d];
  out[(size_t)m*DD + d] = f2bf(v);
}

__global__ void k_init_state(float* __restrict__ ltp, float* __restrict__ act){
  int i = blockIdx.x*256 + threadIdx.x;
  if (i < MS){ ltp[i]=0.f; act[i]=1.f; }
}

// ---------------- MFMA bf16 GEMM, m97 structure ----------------
// grid = (N/128, M/128) so consecutive blocks share the A-tile (XCD L2/L3 locality).
// SCORE=1: no C write; epilogue computes per-row sum of gelu(v)*scW and atomicAdds to tsc.
template<int ACT, int OUTBF, int SCORE>
__global__ __launch_bounds__(256) void k_mgemm(const ushort_t* __restrict__ A,
    const ushort_t* __restrict__ BT, const float* __restrict__ bias,
    float* __restrict__ Cf, ushort_t* __restrict__ Cb,
    const float* __restrict__ scW, float* __restrict__ tsc,
    int M, int N, int K)
{
  __shared__ __align__(16) ushort_t Asm[128*32];   // [row][k]
  __shared__ __align__(16) ushort_t Bsm[128*32];   // [col][k]
  const int tid = threadIdx.x;
  const int lane = tid & 63, wid = tid >> 6;
  const int m0 = blockIdx.y * 128, n0 = blockIdx.x * 128;
  const int wr = (wid>>1)*64, wc = (wid&1)*64;

  f32x4 acc[4][4];
#pragma unroll
  for (int i=0;i<4;i++)
#pragma unroll
    for (int j=0;j<4;j++) acc[i][j] = (f32x4){0.f,0.f,0.f,0.f};

  const int lrow = lane>>2, lk = (lane&3)<<3;
  const ushort_t* Ag0 = A  + (size_t)(m0 + lrow)*K + lk;
  const ushort_t* Bg0 = BT + (size_t)(n0 + lrow)*K + lk;

  for (int k0=0; k0<K; k0+=32){
    __syncthreads();
#pragma unroll
    for (int c2=0; c2<2; ++c2){
      int c = wid + c2*4;
      gload_lds16(Ag0 + (size_t)(c*16)*K + k0, &Asm[c*512]);
      gload_lds16(Bg0 + (size_t)(c*16)*K + k0, &Bsm[c*512]);
    }
    __syncthreads();
    short8 a[4], b[4];
#pragma unroll
    for (int i=0;i<4;i++){
      a[i] = *reinterpret_cast<const short8*>(&Asm[(wr + i*16 + (lane&15))*32 + (lane>>4)*8]);
      b[i] = *reinterpret_cast<const short8*>(&Bsm[(wc + i*16 + (lane&15))*32 + (lane>>4)*8]);
    }
#pragma unroll
    for (int i=0;i<4;i++)
#pragma unroll
      for (int j=0;j<4;j++)
        acc[i][j] = __builtin_amdgcn_mfma_f32_16x16x32_bf16(a[i], b[j], acc[i][j], 0,0,0);
  }

  if (SCORE){
#pragma unroll
    for (int i=0;i<4;i++){
#pragma unroll
      for (int r=0;r<4;r++){
        float rs = 0.f;
#pragma unroll
        for (int j=0;j<4;j++){
          int gn = n0 + wc + j*16 + (lane&15);
          float v = gelu_f(acc[i][j][r] + bias[gn]);
          rs += v * scW[gn];
        }
        rs += __shfl_xor(rs,1); rs += __shfl_xor(rs,2);
        rs += __shfl_xor(rs,4); rs += __shfl_xor(rs,8);
        if ((lane&15)==0){
          int gm = m0 + wr + i*16 + (lane>>4)*4 + r;
          atomicAdd(&tsc[gm], rs);
        }
      }
    }
  } else {
#pragma unroll
    for (int i=0;i<4;i++){
#pragma unroll
      for (int r=0;r<4;r++){
        size_t gm = m0 + wr + i*16 + (lane>>4)*4 + r;
#pragma unroll
        for (int j=0;j<4;j++){
          int gn = n0 + wc + j*16 + (lane&15);
          float v = acc[i][j][r] + bias[gn];
          if (ACT==1) v = gelu_f(v);
          if (OUTBF) Cb[gm*N + gn] = f2bf(v);
          else       Cf[gm*N + gn] = v;
        }
      }
    }
  }
}

// ---------------- LayerNorm (init) ----------------
__global__ __launch_bounds__(256) void k_ln(const float* __restrict__ x, const float* __restrict__ g,
                                            const float* __restrict__ bta, float* __restrict__ out,
                                            ushort_t* __restrict__ cc){
  __shared__ float red[8];
  int m = blockIdx.x, d = threadIdx.x;
  float v = x[(size_t)m*DD + d];
  float s1 = v, s2 = v*v;
  for (int off=32; off; off>>=1){ s1 += __shfl_down(s1,off); s2 += __shfl_down(s2,off); }
  int wid = d >> 6;
  if ((d&63)==0){ red[wid*2]=s1; red[wid*2+1]=s2; }
  __syncthreads();
  float sum = red[0]+red[2]+red[4]+red[6];
  float sq  = red[1]+red[3]+red[5]+red[7];
  float mean = sum * (1.f/DD);
  float var  = sq  * (1.f/DD) - mean*mean;
  float inv  = rsqrtf(fmaxf(var,0.f) + 1e-5f);
  float o = (v-mean)*inv*g[d] + bta[d];
  out[(size_t)m*DD + d] = o;
  cc[(size_t)m*(2*DD) + DD + d] = f2bf(o);
}

// ---------------- fused forward+backward scans ----------------
// grid (NB, 4, 2). Also pre-inits tsc=scb and mx=0 (consumed by conv, after this kernel).
__device__ __forceinline__ void chunk_range(int dir, int ci, int& st, int& ln){
  if (dir==0){ st = ci*CHK; int rem = S2 - st; ln = rem < CHK ? rem : CHK; }
  else { int e = S2 - ci*CHK; st = e - CHK; if (st < 0) st = 0; ln = e - st; }
}

__global__ __launch_bounds__(64) void k_scan(const float* __restrict__ seqp,
    const float* __restrict__ ltpp, const float* __restrict__ actp,
    const float* __restrict__ yes_t, const float* __restrict__ no_t,
    ushort_t* __restrict__ ws5, ushort_t* __restrict__ ccp,
    float* __restrict__ tscp, const float* __restrict__ scb, unsigned* __restrict__ mxp)
{
  __shared__ float s_seq[2][CHK][64];
  __shared__ float s_sc[2][2][CHK];
  const int b = blockIdx.x, dg = blockIdx.y, dir = blockIdx.z, t = threadIdx.x;
  const int d = (dg<<6) + t;
  const float yv = yes_t[d], nv = no_t[d];
  const int nch = (S2 + CHK - 1)/CHK;   // 9

  if (dg==0 && dir==0){
    float sb = scb[0];
    for (int i=t;i<S2;i+=64) tscp[(size_t)b*S2+i] = sb;
    if (b==0 && t==0) *mxp = 0u;
  }

  float4 rv[16]; float rl, ra;

  int st, ln;
  chunk_range(dir, 0, st, ln);
#pragma unroll
  for (int r=0;r<16;r++){
    int j = t + (r<<6); int sl = j>>4; int d4 = (j&15)<<2;
    int srow = st + sl; if (srow > S2-1) srow = S2-1;
    rv[r] = *reinterpret_cast<const float4*>(&seqp[((size_t)b*S2+srow)*DD + (dg<<6) + d4]);
  }
  { int srow = st + t; if (srow > S2-1) srow = S2-1;
    rl = ltpp[(size_t)b*S2+srow]; ra = actp[(size_t)b*S2+srow]; }
#pragma unroll
  for (int r=0;r<16;r++){
    int j = t + (r<<6); int sl=j>>4; int d4=(j&15)<<2;
    *reinterpret_cast<float4*>(&s_seq[0][sl][d4]) = rv[r];
  }
  s_sc[0][0][t]=rl; s_sc[0][1][t]=ra;
  __syncthreads();

  float z1=0.f, z2=0.f, zc=0.f, pb=0.f, ps=0.f, pa=0.f;
  int buf = 0;
  for (int ci=0; ci<nch; ++ci){
    int nst=0, nln=0;
    if (ci+1 < nch){
      chunk_range(dir, ci+1, nst, nln);
#pragma unroll
      for (int r=0;r<16;r++){
        int j = t + (r<<6); int sl=j>>4; int d4=(j&15)<<2;
        int srow = nst + sl; if (srow > S2-1) srow = S2-1;
        rv[r] = *reinterpret_cast<const float4*>(&seqp[((size_t)b*S2+srow)*DD + (dg<<6) + d4]);
      }
      int srow = nst + t; if (srow > S2-1) srow = S2-1;
      rl = ltpp[(size_t)b*S2+srow]; ra = actp[(size_t)b*S2+srow];
    }
    if (dir == 0){
      for (int i=0;i<ln;i++){
        float sv = s_seq[buf][i][t];
        float lt = s_sc[buf][0][i];
        float av = s_sc[buf][1][i];
        float bse = sv + lt*yv + (1.f-lt)*nv;
        float c = pa, f = 1.f - c + EPSF;
        z2 = c*z1 + f*z2;
        z1 = c*pb + f*z1;
        zc = c*ps + f*zc;
        size_t m = (size_t)b*S2 + st + i;
        size_t w5 = m*(5*DD);
        ws5[w5 + d]        = f2bf(z2);
        ws5[w5 + DD + d]   = f2bf(z1);
        ws5[w5 + 2*DD + d] = f2bf(bse);
        ccp[m*(2*DD) + d] = f2bf(zc);
        pb=bse; ps=sv; pa=av;
      }
    } else {
      for (int i=ln-1;i>=0;i--){
        float sv = s_seq[buf][i][t];
        float lt = s_sc[buf][0][i];
        float av = s_sc[buf][1][i];
        float bse = sv + lt*yv + (1.f-lt)*nv;
        float c = pa, f = 1.f - c + EPSF;
        z2 = c*z1 + f*z2;
        z1 = c*pb + f*z1;
        size_t m = (size_t)b*S2 + st + i;
        size_t w5 = m*(5*DD);
        ws5[w5 + 3*DD + d] = f2bf(z1);
        ws5[w5 + 4*DD + d] = f2bf(z2);
        pb=bse; pa=av;
      }
    }
    if (ci+1 < nch){
#pragma unroll
      for (int r=0;r<16;r++){
        int j = t + (r<<6); int sl=j>>4; int d4=(j&15)<<2;
        *reinterpret_cast<float4*>(&s_seq[buf^1][sl][d4]) = rv[r];
      }
      s_sc[buf^1][0][t]=rl; s_sc[buf^1][1][t]=ra;
      st = nst; ln = nln;
    }
    __syncthreads();
    buf ^= 1;
  }
}

// ---------------- global max of tsc (clamped at 0) via uint atomicMax ----------------
__global__ __launch_bounds__(256) void k_maxred(const float* __restrict__ tsc, unsigned* __restrict__ mx){
  __shared__ float red[4];
  int t0 = blockIdx.x*256 + threadIdx.x;
  float v = 0.f;
  for (int i=t0; i<MS; i+=256*32) v = fmaxf(v, tsc[i]);
  for (int off=32; off; off>>=1) v = fmaxf(v, __shfl_down(v,off));
  if ((threadIdx.x&63)==0) red[threadIdx.x>>6]=v;
  __syncthreads();
  if (threadIdx.x==0){
    float r = fmaxf(fmaxf(red[0],red[1]),fmaxf(red[2],red[3]));
    atomicMax(mx, __float_as_uint(r));
  }
}

// ---------------- tp + gates + LN + gated update (contents bf16, lc from cc) ----------
__global__ __launch_bounds__(256) void k_epi(const ushort_t* __restrict__ contents,
     const float* __restrict__ tsc, const unsigned* __restrict__ mx,
     const float* __restrict__ g, const float* __restrict__ bta,
     float* __restrict__ seq, ushort_t* __restrict__ cc, float* __restrict__ ltp){
  __shared__ float red[8];
  int m = blockIdx.x, d = threadIdx.x;
  int s = m % S2;
  float M = __uint_as_float(*mx);
  float sel = (s >= 1 && s <= SS-1) ? 1.f : 0.f;
  float et = expf(tsc[m]-M)*sel;
  float tpv = et/(et+expf(-M)+EPSF);
  if (d==0) ltp[m] = tpv;

  size_t b4 = (size_t)m*HH;
  float lcv = bf2f(cc[(size_t)m*(2*DD) + d]);
  float sv  = seq[(size_t)m*DD+d];
  float g0 = sigmoid_f(bf2f(contents[b4 + d]));
  float g1 = sigmoid_f(bf2f(contents[b4 + DD + d]));
  float g2 = sigmoid_f(bf2f(contents[b4 + 2*DD + d]));
  float pv = bf2f(contents[b4 + 3*DD + d]);
  float x = g0*lcv + g1*sv + g2*pv;
  float s1=x, s2=x*x;
  for (int off=32; off; off>>=1){ s1 += __shfl_down(s1,off); s2 += __shfl_down(s2,off); }
  int wid = d>>6;
  if ((d&63)==0){ red[wid*2]=s1; red[wid*2+1]=s2; }
  __syncthreads();
  float sum=red[0]+red[2]+red[4]+red[6];
  float sq =red[1]+red[3]+red[5]+red[7];
  float mean = sum*(1.f/DD);
  float var  = sq *(1.f/DD)-mean*mean;
  float inv = rsqrtf(fmaxf(var,0.f)+1e-5f);
  float comp = (x-mean)*inv*g[d] + bta[d];
  float o = tpv*comp + (1.f-tpv)*sv;
  seq[(size_t)m*DD+d] = o;
  cc[(size_t)m*(2*DD) + DD + d] = f2bf(o);
}

// ---------------- active update ----------------
__global__ __launch_bounds__(64) void k_actup(const float* __restrict__ tp, float* __restrict__ act){
  __shared__ float sa[S2], st_[S2];
  int b = blockIdx.x, t = threadIdx.x;
  for (int s=t; s<S2; s+=64){ sa[s]=act[(size_t)b*S2+s]; st_[s]=tp[(size_t)b*S2+s]; }
  __syncthreads();
  if (t==0){
    float u = 0.f;
    for (int s=S2-1; s>=0; --s){
      float a = sa[s];
      float na = a*(1.f - a*u);
      sa[s] = fminf(fmaxf(na, 0.f), 1.f);
      u = st_[s] + (1.f-a+EPSF)*u;
    }
  }
  __syncthreads();
  for (int s=t; s<S2; s+=64) act[(size_t)b*S2+s]=sa[s];
}

extern "C" void kernel_launch(void* const* d_in, const int* in_sizes, int n_in,
                              void* d_out, int out_size, void* d_ws, size_t ws_size,
                              hipStream_t stream){
  const float* seq_in = (const float*)d_in[0];
  const float* START = (const float*)d_in[2];
  const float* END   = (const float*)d_in[3];
  const float* yes_t = (const float*)d_in[4];
  const float* no_t  = (const float*)d_in[5];
  const float* convW = (const float*)d_in[6];
  const float* convb = (const float*)d_in[7];
  const float* scW   = (const float*)d_in[8];
  const float* scb   = (const float*)d_in[9];
  const float* itW   = (const float*)d_in[10];
  const float* itb   = (const float*)d_in[11];
  const float* w1W   = (const float*)d_in[12];
  const float* w1b   = (const float*)d_in[13];
  const float* w2W   = (const float*)d_in[14];
  const float* w2b   = (const float*)d_in[15];
  const float* lng   = (const float*)d_in[16];
  const float* lnb   = (const float*)d_in[17];

  char* p = (char*)d_ws;
  float*    seq  = (float*)p;    p += (size_t)MP*DD*4;          // f32 state
  ushort_t* cc   = (ushort_t*)p; p += (size_t)MP*(2*DD)*2;      // bf16 [lc|seq]
  // region A: ws5 bf16 (MP*2560B) / contents bf16 (MP*2048B) / preLN f32 (MP*1024B)
  ushort_t* ws5      = (ushort_t*)p;
  ushort_t* contents = (ushort_t*)p;
  float*    preLN    = (float*)p; p += (size_t)MP*2560;
  // region B: inter bf16 (MP*2048B) / seq0 bf16 (MP*512B)
  ushort_t* inter = (ushort_t*)p;
  ushort_t* seq0  = (ushort_t*)p; p += (size_t)MP*2048;
  ushort_t* itWT   = (ushort_t*)p; p += (size_t)256*256*2;
  ushort_t* convWT = (ushort_t*)p; p += (size_t)256*1280*2;
  ushort_t* w1WT   = (ushort_t*)p; p += (size_t)1024*512*2;
  ushort_t* w2WT   = (ushort_t*)p; p += (size_t)1024*1024*2;
  float* ltp = (float*)p; p += (size_t)MS*4;
  float* act = (float*)p; p += (size_t)MS*4;
  float* tsc = (float*)p; p += (size_t)MP*4;
  unsigned* mx = (unsigned*)p; p += 256;

  dim3 b256(256), b64(64);

  { dim3 g(256/64, 256/64);   k_wt<<<g, b256, 0, stream>>>(itW,  itWT,  256, 256); }
  { dim3 g(1280/64, 256/64);  k_wt<<<g, b256, 0, stream>>>(convW,convWT,1280,256); }
  { dim3 g(512/64, 1024/64);  k_wt<<<g, b256, 0, stream>>>(w1W,  w1WT,  512, 1024); }
  { dim3 g(1024/64, 1024/64); k_wt<<<g, b256, 0, stream>>>(w2W,  w2WT,  1024,1024); }

  k_build_seq0<<<MS, 256, 0, stream>>>(seq_in, START, END, seq0);
  { dim3 g(256/128, MP/128); k_mgemm<0,0,0><<<g, b256, 0, stream>>>(seq0, itWT, itb, preLN, nullptr, nullptr, nullptr, MP, 256, 256); }
  k_ln<<<MS, 256, 0, stream>>>(preLN, lng, lnb, seq, cc);
  k_init_state<<<(MS+255)/256, 256, 0, stream>>>(ltp, act);

  for (int step=0; step<NSTEPS; ++step){
    { dim3 g(NB, 4, 2); k_scan<<<g, b64, 0, stream>>>(seq, ltp, act, yes_t, no_t, ws5, cc, tsc, scb, mx); }
    // conv + fused score: atomicAdd partial gelu(.)·scW into tsc, no C write
    { dim3 g(256/128, MP/128); k_mgemm<0,0,1><<<g, b256, 0, stream>>>(ws5, convWT, convb, nullptr, nullptr, scW, tsc, MP, 256, 5*DD); }
    k_maxred<<<32, b256, 0, stream>>>(tsc, mx);
    // inter = gelu(cc@w1W + w1b)  bf16
    { dim3 g(HH/128, MP/128); k_mgemm<1,1,0><<<g, b256, 0, stream>>>(cc, w1WT, w1b, nullptr, inter, nullptr, nullptr, MP, HH, 2*DD); }
    // contents = inter@w2W + w2b  bf16
    { dim3 g(HH/128, MP/128); k_mgemm<0,1,0><<<g, b256, 0, stream>>>(inter, w2WT, w2b, nullptr, contents, nullptr, nullptr, MP, HH, HH); }
    k_epi<<<MS, 256, 0, stream>>>(contents, tsc, mx, lng, lnb, seq, cc, ltp);
    k_actup<<<NB, b64, 0, stream>>>(ltp, act);
  }
  hipMemcpyAsync(d_out, seq, (size_t)out_size*sizeof(float), hipMemcpyDeviceToDevice, stream);
}

// Round 5
// 1481.198 us; speedup vs baseline: 4.5180x; 1.1730x over previous
//
#include <hip/hip_runtime.h>
#include <math.h>

#define NB 32
#define SS 512
#define S2 514
#define DD 256
#define HH 1024
#define MS (NB*S2)                     // 16448 real rows
#define MP 16512                       // padded to 129*128 for 128-tile GEMM
#define EPSF 1e-9f
#define NSTEPS 6
#define NCH 9                          // scan chunks of 64 rows

typedef unsigned short ushort_t;
typedef __attribute__((ext_vector_type(8))) short short8;
typedef __attribute__((ext_vector_type(4))) float f32x4;

__device__ __forceinline__ float gelu_f(float x){
  float t = tanhf(0.7978845608028654f*(x + 0.044715f*x*x*x));
  return 0.5f*x*(1.f+t);
}
__device__ __forceinline__ float sigmoid_f(float x){ return 1.f/(1.f+expf(-x)); }
__device__ __forceinline__ ushort_t f2bf(float f){
  unsigned u = __float_as_uint(f);
  u += 0x7fffu + ((u>>16)&1u);        // RNE
  return (ushort_t)(u>>16);
}
__device__ __forceinline__ float bf2f(ushort_t b){
  return __uint_as_float(((unsigned)b)<<16);
}
__device__ __forceinline__ void gload_lds16(const void* g, void* l){
  __builtin_amdgcn_global_load_lds((const __attribute__((address_space(1))) void*)g,
                                   (__attribute__((address_space(3))) void*)l, 16, 0, 0);
}

// ---------------- weight transpose + bf16 convert: WT[n][k] = W[k][n] ----------------
__global__ __launch_bounds__(256) void k_wt(const float* __restrict__ W, ushort_t* __restrict__ WT,
                                            int K, int N){
  __shared__ float t[64][65];
  int k0 = blockIdx.x*64, n0 = blockIdx.y*64;
  int tx = threadIdx.x & 63, ty = threadIdx.x >> 6;
#pragma unroll
  for (int i=ty;i<64;i+=4) t[i][tx] = W[(size_t)(k0+i)*N + n0 + tx];
  __syncthreads();
#pragma unroll
  for (int i=ty;i<64;i+=4) WT[(size_t)(n0+i)*K + k0 + tx] = f2bf(t[tx][i]);
}

// ---------------- build padded seq0 in bf16 ----------------
__global__ void k_build_seq0(const float* __restrict__ seq_in, const float* __restrict__ START,
                             const float* __restrict__ END, ushort_t* __restrict__ out){
  int m = blockIdx.x; int d = threadIdx.x;
  int s = m % S2; int b = m / S2;
  float v;
  if (s == 0)        v = START[d];
  else if (s <= SS)  v = seq_in[((size_t)(b*SS + (s-1)))*DD + d];
  else               v = END[d];
  out[(size_t)m*DD + d] = f2bf(v);
}

__global__ void k_init_state(float* __restrict__ ltp, float* __restrict__ act){
  int i = blockIdx.x*256 + threadIdx.x;
  if (i < MS){ ltp[i]=0.f; act[i]=1.f; }
}

// ---------------- MFMA bf16 GEMM, m97 structure ----------------
// grid = (N/128, M/128): consecutive blocks share the A-tile (L2/L3 locality).
// SCORE=1: no C write; epilogue sums gelu(v)*scW per row, atomicAdd into tsc.
template<int ACT, int OUTBF, int SCORE>
__global__ __launch_bounds__(256) void k_mgemm(const ushort_t* __restrict__ A,
    const ushort_t* __restrict__ BT, const float* __restrict__ bias,
    float* __restrict__ Cf, ushort_t* __restrict__ Cb,
    const float* __restrict__ scW, float* __restrict__ tsc,
    int M, int N, int K)
{
  __shared__ __align__(16) ushort_t Asm[128*32];   // [row][k]
  __shared__ __align__(16) ushort_t Bsm[128*32];   // [col][k]
  const int tid = threadIdx.x;
  const int lane = tid & 63, wid = tid >> 6;
  const int m0 = blockIdx.y * 128, n0 = blockIdx.x * 128;
  const int wr = (wid>>1)*64, wc = (wid&1)*64;

  f32x4 acc[4][4];
#pragma unroll
  for (int i=0;i<4;i++)
#pragma unroll
    for (int j=0;j<4;j++) acc[i][j] = (f32x4){0.f,0.f,0.f,0.f};

  const int lrow = lane>>2, lk = (lane&3)<<3;
  const ushort_t* Ag0 = A  + (size_t)(m0 + lrow)*K + lk;
  const ushort_t* Bg0 = BT + (size_t)(n0 + lrow)*K + lk;

  for (int k0=0; k0<K; k0+=32){
    __syncthreads();
#pragma unroll
    for (int c2=0; c2<2; ++c2){
      int c = wid + c2*4;
      gload_lds16(Ag0 + (size_t)(c*16)*K + k0, &Asm[c*512]);
      gload_lds16(Bg0 + (size_t)(c*16)*K + k0, &Bsm[c*512]);
    }
    __syncthreads();
    short8 a[4], b[4];
#pragma unroll
    for (int i=0;i<4;i++){
      a[i] = *reinterpret_cast<const short8*>(&Asm[(wr + i*16 + (lane&15))*32 + (lane>>4)*8]);
      b[i] = *reinterpret_cast<const short8*>(&Bsm[(wc + i*16 + (lane&15))*32 + (lane>>4)*8]);
    }
#pragma unroll
    for (int i=0;i<4;i++)
#pragma unroll
      for (int j=0;j<4;j++)
        acc[i][j] = __builtin_amdgcn_mfma_f32_16x16x32_bf16(a[i], b[j], acc[i][j], 0,0,0);
  }

  if (SCORE){
#pragma unroll
    for (int i=0;i<4;i++){
#pragma unroll
      for (int r=0;r<4;r++){
        float rs = 0.f;
#pragma unroll
        for (int j=0;j<4;j++){
          int gn = n0 + wc + j*16 + (lane&15);
          float v = gelu_f(acc[i][j][r] + bias[gn]);
          rs += v * scW[gn];
        }
        rs += __shfl_xor(rs,1); rs += __shfl_xor(rs,2);
        rs += __shfl_xor(rs,4); rs += __shfl_xor(rs,8);
        if ((lane&15)==0){
          int gm = m0 + wr + i*16 + (lane>>4)*4 + r;
          atomicAdd(&tsc[gm], rs);
        }
      }
    }
  } else {
#pragma unroll
    for (int i=0;i<4;i++){
#pragma unroll
      for (int r=0;r<4;r++){
        size_t gm = m0 + wr + i*16 + (lane>>4)*4 + r;
#pragma unroll
        for (int j=0;j<4;j++){
          int gn = n0 + wc + j*16 + (lane&15);
          float v = acc[i][j][r] + bias[gn];
          if (ACT==1) v = gelu_f(v);
          if (OUTBF) Cb[gm*N + gn] = f2bf(v);
          else       Cf[gm*N + gn] = v;
        }
      }
    }
  }
}

// ---------------- LayerNorm (init) ----------------
__global__ __launch_bounds__(256) void k_ln(const float* __restrict__ x, const float* __restrict__ g,
                                            const float* __restrict__ bta, float* __restrict__ out,
                                            ushort_t* __restrict__ cc){
  __shared__ float red[8];
  int m = blockIdx.x, d = threadIdx.x;
  float v = x[(size_t)m*DD + d];
  float s1 = v, s2 = v*v;
  for (int off=32; off; off>>=1){ s1 += __shfl_down(s1,off); s2 += __shfl_down(s2,off); }
  int wid = d >> 6;
  if ((d&63)==0){ red[wid*2]=s1; red[wid*2+1]=s2; }
  __syncthreads();
  float sum = red[0]+red[2]+red[4]+red[6];
  float sq  = red[1]+red[3]+red[5]+red[7];
  float mean = sum * (1.f/DD);
  float var  = sq  * (1.f/DD) - mean*mean;
  float inv  = rsqrtf(fmaxf(var,0.f) + 1e-5f);
  float o = (v-mean)*inv*g[d] + bta[d];
  out[(size_t)m*DD + d] = o;
  cc[(size_t)m*(2*DD) + DD + d] = f2bf(o);
}

// ---------------- chunked parallel scan ----------------
// Coefficients c=act[prev], f=1-c+eps are d-independent scalars, so a chunk is an
// affine map with scalar matrix [[A,0],[B,A]] (A=prod f) plus per-d local vector.
// PASS 0: local scans from zero -> carry-out vectors + (A,B) scalars.
// PASS 1: local scans + correction Z = local + M_prefix(s)*carry_in -> final bf16 emit.
// grid (NB, 36, 2): y = dg(0..3) | ck(0..8)<<2 ; z = dir. 64 threads.
template<int PASS>
__global__ __launch_bounds__(64) void k_scanchunk(
    const ushort_t* __restrict__ ccp, const float* __restrict__ ltpp, const float* __restrict__ actp,
    const float* __restrict__ yes_t, const float* __restrict__ no_t,
    ushort_t* __restrict__ ws5, ushort_t* __restrict__ ccw,
    float* __restrict__ carry, float* __restrict__ scal)
{
  __shared__ ushort_t s_sv[66][64];
  __shared__ float s_lt[66], s_ac[66];
  const int b = blockIdx.x, dg = blockIdx.y & 3, ck = blockIdx.y >> 2, dir = blockIdx.z, t = threadIdx.x;
  int st, ln;
  if (dir==0){ st = ck*64; ln = (S2 - st < 64) ? (S2 - st) : 64; }
  else { int hi = (S2-1) - ck*64; st = (hi-63 < 0) ? 0 : hi-63; ln = hi - st + 1; }
  const int lo = st - 1;
  const size_t mb = (size_t)b*S2;
  for (int r=0; r<ln+2; ++r){
    int gr = lo + r; gr = gr < 0 ? 0 : (gr > S2-1 ? S2-1 : gr);
    s_sv[r][t] = ccp[(mb+gr)*(2*DD) + DD + (dg<<6) + t];
  }
  for (int r=t; r<ln+2; r+=64){
    int gr = lo + r; gr = gr < 0 ? 0 : (gr > S2-1 ? S2-1 : gr);
    s_lt[r] = ltpp[mb+gr]; s_ac[r] = actp[mb+gr];
  }
  __syncthreads();
  const int d = (dg<<6)+t;
  const float yv = yes_t[d], nv = no_t[d];
  float ci1=0.f, ci2=0.f, cic=0.f;
  const size_t cbase = (((size_t)b*2+dir)*NCH + ck)*3*DD;
  if (PASS==1){
    ci1 = carry[cbase+d]; ci2 = carry[cbase+DD+d];
    if (dir==0) cic = carry[cbase+2*DD+d];
  }
  float A=1.f, Bs=0.f, z1=0.f, z2=0.f, zc=0.f;
  const int pr = (dir==0) ? 0 : (ln+1);
  float svp = bf2f(s_sv[pr][t]); float ltpv = s_lt[pr];
  float pb = svp + ltpv*yv + (1.f-ltpv)*nv, ps = svp, pa = s_ac[pr];
  for (int i=0;i<ln;i++){
    const int r = (dir==0) ? (i+1) : (ln-i);
    const int s = (dir==0) ? (st+i) : (st+ln-1-i);
    float sv = bf2f(s_sv[r][t]); float lt = s_lt[r]; float av = s_ac[r];
    float bse = sv + lt*yv + (1.f-lt)*nv;
    bool upd = (dir==0) ? (s>0) : (s<S2-1);
    if (upd){
      float c = pa, f = 1.f-c+EPSF;
      z2 = c*z1 + f*z2;          // second-hop uses first-hop's OLD value
      z1 = c*pb + f*z1;
      zc = c*ps + f*zc;
      Bs = c*A + f*Bs; A = f*A;  // M_new = M_s * M_old
    }
    if (PASS==1){
      size_t m = mb + s; size_t w5 = m*(5*DD);
      float Z1 = z1 + A*ci1, Z2 = z2 + Bs*ci1 + A*ci2;
      if (dir==0){
        float Zc = zc + A*cic;
        ws5[w5 + d]        = f2bf(Z2);
        ws5[w5 + DD + d]   = f2bf(Z1);
        ws5[w5 + 2*DD + d] = f2bf(bse);
        ccw[m*(2*DD) + d]  = f2bf(Zc);
      } else {
        ws5[w5 + 3*DD + d] = f2bf(Z1);
        ws5[w5 + 4*DD + d] = f2bf(Z2);
      }
    }
    pb=bse; ps=sv; pa=av;
  }
  if (PASS==0){
    carry[cbase+d] = z1; carry[cbase+DD+d] = z2;
    if (dir==0) carry[cbase+2*DD+d] = zc;
    if (dg==0 && t==0){ size_t sb = (((size_t)b*2+dir)*NCH+ck)*2; scal[sb]=A; scal[sb+1]=Bs; }
  }
}

// combine carries across chunks (9 affine steps); also pre-inits tsc=scb and mx=0.
__global__ __launch_bounds__(64) void k_scancomb(const float* __restrict__ cl, float* __restrict__ cin,
    const float* __restrict__ scal, float* __restrict__ tscp, const float* __restrict__ scb,
    unsigned* __restrict__ mxp)
{
  const int b = blockIdx.x, dg = blockIdx.y, dir = blockIdx.z, t = threadIdx.x;
  const int d = (dg<<6)+t;
  if (dir==0 && dg==0){
    float sbv = scb[0];
    for (int i=t;i<S2;i+=64) tscp[(size_t)b*S2+i]=sbv;
    if (b==0 && t==0) *mxp = 0u;
  }
  float s1=0.f,s2=0.f,sc=0.f;
  for (int k=0;k<NCH;k++){
    size_t cbase = (((size_t)b*2+dir)*NCH+k)*3*DD;
    cin[cbase+d]=s1; cin[cbase+DD+d]=s2; if(dir==0) cin[cbase+2*DD+d]=sc;
    size_t sb = (((size_t)b*2+dir)*NCH+k)*2;
    float A = scal[sb], Bs = scal[sb+1];
    float l1 = cl[cbase+d], l2 = cl[cbase+DD+d];
    float ns1 = l1 + A*s1;
    float ns2 = l2 + Bs*s1 + A*s2;
    if (dir==0){ float lcv = cl[cbase+2*DD+d]; sc = lcv + A*sc; }
    s1=ns1; s2=ns2;
  }
}

// ---------------- global max of tsc (clamped at 0) ----------------
__global__ __launch_bounds__(256) void k_maxred(const float* __restrict__ tsc, unsigned* __restrict__ mx){
  __shared__ float red[4];
  int t0 = blockIdx.x*256 + threadIdx.x;
  float v = 0.f;
  for (int i=t0; i<MS; i+=256*32) v = fmaxf(v, tsc[i]);
  for (int off=32; off; off>>=1) v = fmaxf(v, __shfl_down(v,off));
  if ((threadIdx.x&63)==0) red[threadIdx.x>>6]=v;
  __syncthreads();
  if (threadIdx.x==0){
    float r = fmaxf(fmaxf(red[0],red[1]),fmaxf(red[2],red[3]));
    atomicMax(mx, __float_as_uint(r));
  }
}

// ---------------- tp + gates + LN + gated update ----------------
__global__ __launch_bounds__(256) void k_epi(const ushort_t* __restrict__ contents,
     const float* __restrict__ tsc, const unsigned* __restrict__ mx,
     const float* __restrict__ g, const float* __restrict__ bta,
     float* __restrict__ seq, ushort_t* __restrict__ cc, float* __restrict__ ltp){
  __shared__ float red[8];
  int m = blockIdx.x, d = threadIdx.x;
  int s = m % S2;
  float M = __uint_as_float(*mx);
  float sel = (s >= 1 && s <= SS-1) ? 1.f : 0.f;
  float et = expf(tsc[m]-M)*sel;
  float tpv = et/(et+expf(-M)+EPSF);
  if (d==0) ltp[m] = tpv;

  size_t b4 = (size_t)m*HH;
  float lcv = bf2f(cc[(size_t)m*(2*DD) + d]);
  float sv  = seq[(size_t)m*DD+d];
  float g0 = sigmoid_f(bf2f(contents[b4 + d]));
  float g1 = sigmoid_f(bf2f(contents[b4 + DD + d]));
  float g2 = sigmoid_f(bf2f(contents[b4 + 2*DD + d]));
  float pv = bf2f(contents[b4 + 3*DD + d]);
  float x = g0*lcv + g1*sv + g2*pv;
  float s1=x, s2=x*x;
  for (int off=32; off; off>>=1){ s1 += __shfl_down(s1,off); s2 += __shfl_down(s2,off); }
  int wid = d>>6;
  if ((d&63)==0){ red[wid*2]=s1; red[wid*2+1]=s2; }
  __syncthreads();
  float sum=red[0]+red[2]+red[4]+red[6];
  float sq =red[1]+red[3]+red[5]+red[7];
  float mean = sum*(1.f/DD);
  float var  = sq *(1.f/DD)-mean*mean;
  float inv = rsqrtf(fmaxf(var,0.f)+1e-5f);
  float comp = (x-mean)*inv*g[d] + bta[d];
  float o = tpv*comp + (1.f-tpv)*sv;
  seq[(size_t)m*DD+d] = o;
  cc[(size_t)m*(2*DD) + DD + d] = f2bf(o);
}

// ---------------- active update: lane-segmented affine scan + shfl combine ----------
__global__ __launch_bounds__(64) void k_actup(const float* __restrict__ tp, float* __restrict__ act){
  __shared__ float s_a[S2], s_t[S2], s_o[S2];
  int b = blockIdx.x, t = threadIdx.x;
  for (int s=t;s<S2;s+=64){ s_a[s]=act[(size_t)b*S2+s]; s_t[s]=tp[(size_t)b*S2+s]; }
  __syncthreads();
  // lane t covers descending positions [max(513-9t-8,0), 513-9t]
  int hi = (S2-1) - 9*t;
  int lo = hi - 8; if (lo < 0) lo = 0;
  float A=1.f, Bv=0.f;
  if (hi >= 0){
    for (int s=hi; s>=lo; --s){
      float f = 1.f - s_a[s] + EPSF;
      Bv = s_t[s] + f*Bv; A = f*A;
    }
  }
  // inclusive affine scan across lanes (lane 0 = highest positions)
  float Ai=A, Bi=Bv;
  for (int off=1; off<64; off<<=1){
    float Ao = __shfl_up(Ai, off), Bo = __shfl_up(Bi, off);
    if (t >= off){ Bi = Bi + Ai*Bo; Ai = Ai*Ao; }
  }
  float uin = __shfl_up(Bi, 1); if (t==0) uin = 0.f;
  if (hi >= 0){
    float u = uin;
    for (int s=hi; s>=lo; --s){
      float a = s_a[s];
      float na = a*(1.f - a*u);
      s_o[s] = fminf(fmaxf(na,0.f),1.f);
      u = s_t[s] + (1.f - a + EPSF)*u;
    }
  }
  __syncthreads();
  for (int s=t;s<S2;s+=64) act[(size_t)b*S2+s]=s_o[s];
}

extern "C" void kernel_launch(void* const* d_in, const int* in_sizes, int n_in,
                              void* d_out, int out_size, void* d_ws, size_t ws_size,
                              hipStream_t stream){
  const float* seq_in = (const float*)d_in[0];
  const float* START = (const float*)d_in[2];
  const float* END   = (const float*)d_in[3];
  const float* yes_t = (const float*)d_in[4];
  const float* no_t  = (const float*)d_in[5];
  const float* convW = (const float*)d_in[6];
  const float* convb = (const float*)d_in[7];
  const float* scW   = (const float*)d_in[8];
  const float* scb   = (const float*)d_in[9];
  const float* itW   = (const float*)d_in[10];
  const float* itb   = (const float*)d_in[11];
  const float* w1W   = (const float*)d_in[12];
  const float* w1b   = (const float*)d_in[13];
  const float* w2W   = (const float*)d_in[14];
  const float* w2b   = (const float*)d_in[15];
  const float* lng   = (const float*)d_in[16];
  const float* lnb   = (const float*)d_in[17];

  char* p = (char*)d_ws;
  float*    seq  = (float*)p;    p += (size_t)MP*DD*4;          // f32 state
  ushort_t* cc   = (ushort_t*)p; p += (size_t)MP*(2*DD)*2;      // bf16 [lc|seq]
  // region A: ws5 bf16 (MP*2560B) / contents bf16 (MP*2048B) / preLN f32 (MP*1024B)
  ushort_t* ws5      = (ushort_t*)p;
  ushort_t* contents = (ushort_t*)p;
  float*    preLN    = (float*)p; p += (size_t)MP*2560;
  // region B: inter bf16 (MP*2048B) / seq0 bf16 (MP*512B)
  ushort_t* inter = (ushort_t*)p;
  ushort_t* seq0  = (ushort_t*)p; p += (size_t)MP*2048;
  ushort_t* itWT   = (ushort_t*)p; p += (size_t)256*256*2;
  ushort_t* convWT = (ushort_t*)p; p += (size_t)256*1280*2;
  ushort_t* w1WT   = (ushort_t*)p; p += (size_t)1024*512*2;
  ushort_t* w2WT   = (ushort_t*)p; p += (size_t)1024*1024*2;
  float* ltp = (float*)p; p += (size_t)MS*4;
  float* act = (float*)p; p += (size_t)MS*4;
  float* tsc = (float*)p; p += (size_t)MP*4;
  unsigned* mx = (unsigned*)p; p += 256;
  float* carryL = (float*)p; p += (size_t)NB*2*NCH*3*DD*4;   // chunk-local carry-out
  float* carryI = (float*)p; p += (size_t)NB*2*NCH*3*DD*4;   // carry-in per chunk
  float* scal   = (float*)p; p += (size_t)NB*2*NCH*2*4;      // (A,B) scalars

  dim3 b256(256), b64(64);

  { dim3 g(256/64, 256/64);   k_wt<<<g, b256, 0, stream>>>(itW,  itWT,  256, 256); }
  { dim3 g(1280/64, 256/64);  k_wt<<<g, b256, 0, stream>>>(convW,convWT,1280,256); }
  { dim3 g(512/64, 1024/64);  k_wt<<<g, b256, 0, stream>>>(w1W,  w1WT,  512, 1024); }
  { dim3 g(1024/64, 1024/64); k_wt<<<g, b256, 0, stream>>>(w2W,  w2WT,  1024,1024); }

  k_build_seq0<<<MS, 256, 0, stream>>>(seq_in, START, END, seq0);
  { dim3 g(256/128, MP/128); k_mgemm<0,0,0><<<g, b256, 0, stream>>>(seq0, itWT, itb, preLN, nullptr, nullptr, nullptr, MP, 256, 256); }
  k_ln<<<MS, 256, 0, stream>>>(preLN, lng, lnb, seq, cc);
  k_init_state<<<(MS+255)/256, 256, 0, stream>>>(ltp, act);

  for (int step=0; step<NSTEPS; ++step){
    { dim3 g(NB, 4*NCH, 2);
      k_scanchunk<0><<<g, b64, 0, stream>>>(cc, ltp, act, yes_t, no_t, ws5, cc, carryL, scal); }
    { dim3 g(NB, 4, 2);
      k_scancomb<<<g, b64, 0, stream>>>(carryL, carryI, scal, tsc, scb, mx); }
    { dim3 g(NB, 4*NCH, 2);
      k_scanchunk<1><<<g, b64, 0, stream>>>(cc, ltp, act, yes_t, no_t, ws5, cc, carryI, scal); }
    // conv + fused score
    { dim3 g(256/128, MP/128); k_mgemm<0,0,1><<<g, b256, 0, stream>>>(ws5, convWT, convb, nullptr, nullptr, scW, tsc, MP, 256, 5*DD); }
    k_maxred<<<32, b256, 0, stream>>>(tsc, mx);
    // inter = gelu(cc@w1W + w1b)  bf16
    { dim3 g(HH/128, MP/128); k_mgemm<1,1,0><<<g, b256, 0, stream>>>(cc, w1WT, w1b, nullptr, inter, nullptr, nullptr, MP, HH, 2*DD); }
    // contents = inter@w2W + w2b  bf16
    { dim3 g(HH/128, MP/128); k_mgemm<0,1,0><<<g, b256, 0, stream>>>(inter, w2WT, w2b, nullptr, contents, nullptr, nullptr, MP, HH, HH); }
    k_epi<<<MS, 256, 0, stream>>>(contents, tsc, mx, lng, lnb, seq, cc, ltp);
    k_actup<<<NB, b64, 0, stream>>>(ltp, act);
  }
  hipMemcpyAsync(d_out, seq, (size_t)out_size*sizeof(float), hipMemcpyDeviceToDevice, stream);
}

// Round 6
// 1403.927 us; speedup vs baseline: 4.7666x; 1.0550x over previous
//
#include <hip/hip_runtime.h>
#include <math.h>

#define NB 32
#define SS 512
#define S2 514
#define DD 256
#define HH 1024
#define MS (NB*S2)                     // 16448 real rows
#define MP 16512                       // padded to 129*128 for 128-tile GEMM
#define EPSF 1e-9f
#define NSTEPS 6
#define NCH 9                          // scan chunks of 64 rows

typedef unsigned short ushort_t;
typedef __attribute__((ext_vector_type(8))) short short8;
typedef __attribute__((ext_vector_type(4))) float f32x4;

__device__ __forceinline__ float gelu_f(float x){
  float t = tanhf(0.7978845608028654f*(x + 0.044715f*x*x*x));
  return 0.5f*x*(1.f+t);
}
__device__ __forceinline__ float sigmoid_f(float x){ return 1.f/(1.f+expf(-x)); }
__device__ __forceinline__ ushort_t f2bf(float f){
  unsigned u = __float_as_uint(f);
  u += 0x7fffu + ((u>>16)&1u);        // RNE
  return (ushort_t)(u>>16);
}
__device__ __forceinline__ float bf2f(ushort_t b){
  return __uint_as_float(((unsigned)b)<<16);
}
__device__ __forceinline__ void gload_lds16(const void* g, void* l){
  __builtin_amdgcn_global_load_lds((const __attribute__((address_space(1))) void*)g,
                                   (__attribute__((address_space(3))) void*)l, 16, 0, 0);
}

// ---------------- weight transpose + bf16 convert: WT[n][k] = W[k][n] ----------------
__global__ __launch_bounds__(256) void k_wt(const float* __restrict__ W, ushort_t* __restrict__ WT,
                                            int K, int N){
  __shared__ float t[64][65];
  int k0 = blockIdx.x*64, n0 = blockIdx.y*64;
  int tx = threadIdx.x & 63, ty = threadIdx.x >> 6;
#pragma unroll
  for (int i=ty;i<64;i+=4) t[i][tx] = W[(size_t)(k0+i)*N + n0 + tx];
  __syncthreads();
#pragma unroll
  for (int i=ty;i<64;i+=4) WT[(size_t)(n0+i)*K + k0 + tx] = f2bf(t[tx][i]);
}

// ---------------- build padded seq0 in bf16 ----------------
__global__ void k_build_seq0(const float* __restrict__ seq_in, const float* __restrict__ START,
                             const float* __restrict__ END, ushort_t* __restrict__ out){
  int m = blockIdx.x; int d = threadIdx.x;
  int s = m % S2; int b = m / S2;
  float v;
  if (s == 0)        v = START[d];
  else if (s <= SS)  v = seq_in[((size_t)(b*SS + (s-1)))*DD + d];
  else               v = END[d];
  out[(size_t)m*DD + d] = f2bf(v);
}

__global__ void k_init_state(float* __restrict__ ltp, float* __restrict__ act){
  int i = blockIdx.x*256 + threadIdx.x;
  if (i < MS){ ltp[i]=0.f; act[i]=1.f; }
}

// ---------------- MFMA bf16 GEMM: 128x128 tile, BK=64, XCD-swizzled 1D grid ----------
// LDS XOR-swizzle (both-sides): linear gload_lds dest + pre-swizzled global source
// chunk ((lane&7)^(lane>>3)), reads use slot ((kk*4+hi)^(row&7)) -> 2-way banks (free).
// Grid: flat nwg = (N/128)*(M/128); bijective XCD chunking (m204) so the N-blocks
// sharing one A-panel execute on the SAME XCD (A-panel stays L2-resident).
// SCORE=1: no C write; epilogue sums gelu(v)*scW per row, atomicAdd into tsc.
template<int ACT, int OUTBF, int SCORE>
__global__ __launch_bounds__(256) void k_mgemm(const ushort_t* __restrict__ A,
    const ushort_t* __restrict__ BT, const float* __restrict__ bias,
    float* __restrict__ Cf, ushort_t* __restrict__ Cb,
    const float* __restrict__ scW, float* __restrict__ tsc,
    int M, int N, int K)
{
  __shared__ __align__(16) ushort_t Asm[128*64];   // [row][k] (k XOR-swizzled per row)
  __shared__ __align__(16) ushort_t Bsm[128*64];   // [col][k]
  const int tid = threadIdx.x;
  const int lane = tid & 63, wid = tid >> 6;

  // bijective XCD swizzle: XCD x gets a contiguous chunk of logical tile space
  {
  }
  const int nwg = gridDim.x, f = blockIdx.x;
  const int q = nwg >> 3, r = nwg & 7;
  const int x = f & 7, jj = f >> 3;
  const int logical = (x < r ? x*(q+1) : r*(q+1) + (x-r)*q) + jj;
  const int NX = N >> 7;
  const int bx = logical % NX, by = logical / NX;
  const int m0 = by * 128, n0 = bx * 128;
  const int wr = (wid>>1)*64, wc = (wid&1)*64;

  f32x4 acc[4][4];
#pragma unroll
  for (int i=0;i<4;i++)
#pragma unroll
    for (int j=0;j<4;j++) acc[i][j] = (f32x4){0.f,0.f,0.f,0.f};

  // staging: 16 chunks of 1KB per matrix; wave stages chunks {wid+4t}; lane covers
  // row lane>>3 of the chunk, source col pre-swizzled by (lane&7)^(lane>>3).
  const int srow = lane >> 3;
  const int scol = (((lane&7) ^ (lane>>3)) << 3);
  const int rrow = lane & 15, rhi = lane >> 4;

  for (int k0=0; k0<K; k0+=64){
    __syncthreads();                                 // prev step's ds_reads done
#pragma unroll
    for (int t=0;t<4;t++){
      int c = wid + 4*t;
      gload_lds16(A  + (size_t)(m0 + c*8 + srow)*K + k0 + scol, &Asm[c*512]);
      gload_lds16(BT + (size_t)(n0 + c*8 + srow)*K + k0 + scol, &Bsm[c*512]);
    }
    __syncthreads();                                 // vmcnt drained -> LDS ready
#pragma unroll
    for (int kk=0; kk<2; ++kk){
      short8 a[4], b[4];
#pragma unroll
      for (int i=0;i<4;i++){
        int ra = wr + i*16 + rrow;
        int sa = (((kk<<2) + rhi) ^ (ra & 7)) << 3;
        a[i] = *reinterpret_cast<const short8*>(&Asm[ra*64 + sa]);
        int rb = wc + i*16 + rrow;
        int sb = (((kk<<2) + rhi) ^ (rb & 7)) << 3;
        b[i] = *reinterpret_cast<const short8*>(&Bsm[rb*64 + sb]);
      }
#pragma unroll
      for (int i=0;i<4;i++)
#pragma unroll
        for (int j=0;j<4;j++)
          acc[i][j] = __builtin_amdgcn_mfma_f32_16x16x32_bf16(a[i], b[j], acc[i][j], 0,0,0);
    }
  }

  if (SCORE){
#pragma unroll
    for (int i=0;i<4;i++){
#pragma unroll
      for (int rreg=0;rreg<4;rreg++){
        float rs = 0.f;
#pragma unroll
        for (int j=0;j<4;j++){
          int gn = n0 + wc + j*16 + (lane&15);
          float v = gelu_f(acc[i][j][rreg] + bias[gn]);
          rs += v * scW[gn];
        }
        rs += __shfl_xor(rs,1); rs += __shfl_xor(rs,2);
        rs += __shfl_xor(rs,4); rs += __shfl_xor(rs,8);
        if ((lane&15)==0){
          int gm = m0 + wr + i*16 + (lane>>4)*4 + rreg;
          atomicAdd(&tsc[gm], rs);
        }
      }
    }
  } else {
#pragma unroll
    for (int i=0;i<4;i++){
#pragma unroll
      for (int rreg=0;rreg<4;rreg++){
        size_t gm = m0 + wr + i*16 + (lane>>4)*4 + rreg;
#pragma unroll
        for (int j=0;j<4;j++){
          int gn = n0 + wc + j*16 + (lane&15);
          float v = acc[i][j][rreg] + bias[gn];
          if (ACT==1) v = gelu_f(v);
          if (OUTBF) Cb[gm*N + gn] = f2bf(v);
          else       Cf[gm*N + gn] = v;
        }
      }
    }
  }
}

// ---------------- LayerNorm (init) ----------------
__global__ __launch_bounds__(256) void k_ln(const float* __restrict__ x, const float* __restrict__ g,
                                            const float* __restrict__ bta, float* __restrict__ out,
                                            ushort_t* __restrict__ cc){
  __shared__ float red[8];
  int m = blockIdx.x, d = threadIdx.x;
  float v = x[(size_t)m*DD + d];
  float s1 = v, s2 = v*v;
  for (int off=32; off; off>>=1){ s1 += __shfl_down(s1,off); s2 += __shfl_down(s2,off); }
  int wid = d >> 6;
  if ((d&63)==0){ red[wid*2]=s1; red[wid*2+1]=s2; }
  __syncthreads();
  float sum = red[0]+red[2]+red[4]+red[6];
  float sq  = red[1]+red[3]+red[5]+red[7];
  float mean = sum * (1.f/DD);
  float var  = sq  * (1.f/DD) - mean*mean;
  float inv  = rsqrtf(fmaxf(var,0.f) + 1e-5f);
  float o = (v-mean)*inv*g[d] + bta[d];
  out[(size_t)m*DD + d] = o;
  cc[(size_t)m*(2*DD) + DD + d] = f2bf(o);
}

// ---------------- chunked parallel scan ----------------
template<int PASS>
__global__ __launch_bounds__(64) void k_scanchunk(
    const ushort_t* __restrict__ ccp, const float* __restrict__ ltpp, const float* __restrict__ actp,
    const float* __restrict__ yes_t, const float* __restrict__ no_t,
    ushort_t* __restrict__ ws5, ushort_t* __restrict__ ccw,
    float* __restrict__ carry, float* __restrict__ scal)
{
  __shared__ ushort_t s_sv[66][64];
  __shared__ float s_lt[66], s_ac[66];
  const int b = blockIdx.x, dg = blockIdx.y & 3, ck = blockIdx.y >> 2, dir = blockIdx.z, t = threadIdx.x;
  int st, ln;
  if (dir==0){ st = ck*64; ln = (S2 - st < 64) ? (S2 - st) : 64; }
  else { int hi = (S2-1) - ck*64; st = (hi-63 < 0) ? 0 : hi-63; ln = hi - st + 1; }
  const int lo = st - 1;
  const size_t mb = (size_t)b*S2;
  for (int r=0; r<ln+2; ++r){
    int gr = lo + r; gr = gr < 0 ? 0 : (gr > S2-1 ? S2-1 : gr);
    s_sv[r][t] = ccp[(mb+gr)*(2*DD) + DD + (dg<<6) + t];
  }
  for (int r=t; r<ln+2; r+=64){
    int gr = lo + r; gr = gr < 0 ? 0 : (gr > S2-1 ? S2-1 : gr);
    s_lt[r] = ltpp[mb+gr]; s_ac[r] = actp[mb+gr];
  }
  __syncthreads();
  const int d = (dg<<6)+t;
  const float yv = yes_t[d], nv = no_t[d];
  float ci1=0.f, ci2=0.f, cic=0.f;
  const size_t cbase = (((size_t)b*2+dir)*NCH + ck)*3*DD;
  if (PASS==1){
    ci1 = carry[cbase+d]; ci2 = carry[cbase+DD+d];
    if (dir==0) cic = carry[cbase+2*DD+d];
  }
  float A=1.f, Bs=0.f, z1=0.f, z2=0.f, zc=0.f;
  const int pr = (dir==0) ? 0 : (ln+1);
  float svp = bf2f(s_sv[pr][t]); float ltpv = s_lt[pr];
  float pb = svp + ltpv*yv + (1.f-ltpv)*nv, ps = svp, pa = s_ac[pr];
  for (int i=0;i<ln;i++){
    const int r = (dir==0) ? (i+1) : (ln-i);
    const int s = (dir==0) ? (st+i) : (st+ln-1-i);
    float sv = bf2f(s_sv[r][t]); float lt = s_lt[r]; float av = s_ac[r];
    float bse = sv + lt*yv + (1.f-lt)*nv;
    bool upd = (dir==0) ? (s>0) : (s<S2-1);
    if (upd){
      float c = pa, fc = 1.f-c+EPSF;
      z2 = c*z1 + fc*z2;
      z1 = c*pb + fc*z1;
      zc = c*ps + fc*zc;
      Bs = c*A + fc*Bs; A = fc*A;
    }
    if (PASS==1){
      size_t m = mb + s; size_t w5 = m*(5*DD);
      float Z1 = z1 + A*ci1, Z2 = z2 + Bs*ci1 + A*ci2;
      if (dir==0){
        float Zc = zc + A*cic;
        ws5[w5 + d]        = f2bf(Z2);
        ws5[w5 + DD + d]   = f2bf(Z1);
        ws5[w5 + 2*DD + d] = f2bf(bse);
        ccw[m*(2*DD) + d]  = f2bf(Zc);
      } else {
        ws5[w5 + 3*DD + d] = f2bf(Z1);
        ws5[w5 + 4*DD + d] = f2bf(Z2);
      }
    }
    pb=bse; ps=sv; pa=av;
  }
  if (PASS==0){
    carry[cbase+d] = z1; carry[cbase+DD+d] = z2;
    if (dir==0) carry[cbase+2*DD+d] = zc;
    if (dg==0 && t==0){ size_t sb = (((size_t)b*2+dir)*NCH+ck)*2; scal[sb]=A; scal[sb+1]=Bs; }
  }
}

// combine carries across chunks; also pre-inits tsc=scb and mx=0.
__global__ __launch_bounds__(64) void k_scancomb(const float* __restrict__ cl, float* __restrict__ cin,
    const float* __restrict__ scal, float* __restrict__ tscp, const float* __restrict__ scb,
    unsigned* __restrict__ mxp)
{
  const int b = blockIdx.x, dg = blockIdx.y, dir = blockIdx.z, t = threadIdx.x;
  const int d = (dg<<6)+t;
  if (dir==0 && dg==0){
    float sbv = scb[0];
    for (int i=t;i<S2;i+=64) tscp[(size_t)b*S2+i]=sbv;
    if (b==0 && t==0) *mxp = 0u;
  }
  float s1=0.f,s2=0.f,sc=0.f;
  for (int k=0;k<NCH;k++){
    size_t cbase = (((size_t)b*2+dir)*NCH+k)*3*DD;
    cin[cbase+d]=s1; cin[cbase+DD+d]=s2; if(dir==0) cin[cbase+2*DD+d]=sc;
    size_t sb = (((size_t)b*2+dir)*NCH+k)*2;
    float A = scal[sb], Bs = scal[sb+1];
    float l1 = cl[cbase+d], l2 = cl[cbase+DD+d];
    float ns1 = l1 + A*s1;
    float ns2 = l2 + Bs*s1 + A*s2;
    if (dir==0){ float lcv = cl[cbase+2*DD+d]; sc = lcv + A*sc; }
    s1=ns1; s2=ns2;
  }
}

// ---------------- global max of tsc (clamped at 0) ----------------
__global__ __launch_bounds__(256) void k_maxred(const float* __restrict__ tsc, unsigned* __restrict__ mx){
  __shared__ float red[4];
  int t0 = blockIdx.x*256 + threadIdx.x;
  float v = 0.f;
  for (int i=t0; i<MS; i+=256*32) v = fmaxf(v, tsc[i]);
  for (int off=32; off; off>>=1) v = fmaxf(v, __shfl_down(v,off));
  if ((threadIdx.x&63)==0) red[threadIdx.x>>6]=v;
  __syncthreads();
  if (threadIdx.x==0){
    float r = fmaxf(fmaxf(red[0],red[1]),fmaxf(red[2],red[3]));
    atomicMax(mx, __float_as_uint(r));
  }
}

// ---------------- tp + gates + LN + gated update ----------------
__global__ __launch_bounds__(256) void k_epi(const ushort_t* __restrict__ contents,
     const float* __restrict__ tsc, const unsigned* __restrict__ mx,
     const float* __restrict__ g, const float* __restrict__ bta,
     float* __restrict__ seq, ushort_t* __restrict__ cc, float* __restrict__ ltp){
  __shared__ float red[8];
  int m = blockIdx.x, d = threadIdx.x;
  int s = m % S2;
  float M = __uint_as_float(*mx);
  float sel = (s >= 1 && s <= SS-1) ? 1.f : 0.f;
  float et = expf(tsc[m]-M)*sel;
  float tpv = et/(et+expf(-M)+EPSF);
  if (d==0) ltp[m] = tpv;

  size_t b4 = (size_t)m*HH;
  float lcv = bf2f(cc[(size_t)m*(2*DD) + d]);
  float sv  = seq[(size_t)m*DD+d];
  float g0 = sigmoid_f(bf2f(contents[b4 + d]));
  float g1 = sigmoid_f(bf2f(contents[b4 + DD + d]));
  float g2 = sigmoid_f(bf2f(contents[b4 + 2*DD + d]));
  float pv = bf2f(contents[b4 + 3*DD + d]);
  float xv = g0*lcv + g1*sv + g2*pv;
  float s1=xv, s2=xv*xv;
  for (int off=32; off; off>>=1){ s1 += __shfl_down(s1,off); s2 += __shfl_down(s2,off); }
  int wid = d>>6;
  if ((d&63)==0){ red[wid*2]=s1; red[wid*2+1]=s2; }
  __syncthreads();
  float sum=red[0]+red[2]+red[4]+red[6];
  float sq =red[1]+red[3]+red[5]+red[7];
  float mean = sum*(1.f/DD);
  float var  = sq *(1.f/DD)-mean*mean;
  float inv = rsqrtf(fmaxf(var,0.f)+1e-5f);
  float comp = (xv-mean)*inv*g[d] + bta[d];
  float o = tpv*comp + (1.f-tpv)*sv;
  seq[(size_t)m*DD+d] = o;
  cc[(size_t)m*(2*DD) + DD + d] = f2bf(o);
}

// ---------------- active update: lane-segmented affine scan + shfl combine ----------
__global__ __launch_bounds__(64) void k_actup(const float* __restrict__ tp, float* __restrict__ act){
  __shared__ float s_a[S2], s_t[S2], s_o[S2];
  int b = blockIdx.x, t = threadIdx.x;
  for (int s=t;s<S2;s+=64){ s_a[s]=act[(size_t)b*S2+s]; s_t[s]=tp[(size_t)b*S2+s]; }
  __syncthreads();
  int hi = (S2-1) - 9*t;
  int lo = hi - 8; if (lo < 0) lo = 0;
  float A=1.f, Bv=0.f;
  if (hi >= 0){
    for (int s=hi; s>=lo; --s){
      float fc = 1.f - s_a[s] + EPSF;
      Bv = s_t[s] + fc*Bv; A = fc*A;
    }
  }
  float Ai=A, Bi=Bv;
  for (int off=1; off<64; off<<=1){
    float Ao = __shfl_up(Ai, off), Bo = __shfl_up(Bi, off);
    if (t >= off){ Bi = Bi + Ai*Bo; Ai = Ai*Ao; }
  }
  float uin = __shfl_up(Bi, 1); if (t==0) uin = 0.f;
  if (hi >= 0){
    float u = uin;
    for (int s=hi; s>=lo; --s){
      float a = s_a[s];
      float na = a*(1.f - a*u);
      s_o[s] = fminf(fmaxf(na,0.f),1.f);
      u = s_t[s] + (1.f - a + EPSF)*u;
    }
  }
  __syncthreads();
  for (int s=t;s<S2;s+=64) act[(size_t)b*S2+s]=s_o[s];
}

extern "C" void kernel_launch(void* const* d_in, const int* in_sizes, int n_in,
                              void* d_out, int out_size, void* d_ws, size_t ws_size,
                              hipStream_t stream){
  const float* seq_in = (const float*)d_in[0];
  const float* START = (const float*)d_in[2];
  const float* END   = (const float*)d_in[3];
  const float* yes_t = (const float*)d_in[4];
  const float* no_t  = (const float*)d_in[5];
  const float* convW = (const float*)d_in[6];
  const float* convb = (const float*)d_in[7];
  const float* scW   = (const float*)d_in[8];
  const float* scb   = (const float*)d_in[9];
  const float* itW   = (const float*)d_in[10];
  const float* itb   = (const float*)d_in[11];
  const float* w1W   = (const float*)d_in[12];
  const float* w1b   = (const float*)d_in[13];
  const float* w2W   = (const float*)d_in[14];
  const float* w2b   = (const float*)d_in[15];
  const float* lng   = (const float*)d_in[16];
  const float* lnb   = (const float*)d_in[17];

  char* p = (char*)d_ws;
  float*    seq  = (float*)p;    p += (size_t)MP*DD*4;          // f32 state
  ushort_t* cc   = (ushort_t*)p; p += (size_t)MP*(2*DD)*2;      // bf16 [lc|seq]
  ushort_t* ws5      = (ushort_t*)p;
  ushort_t* contents = (ushort_t*)p;
  float*    preLN    = (float*)p; p += (size_t)MP*2560;
  ushort_t* inter = (ushort_t*)p;
  ushort_t* seq0  = (ushort_t*)p; p += (size_t)MP*2048;
  ushort_t* itWT   = (ushort_t*)p; p += (size_t)256*256*2;
  ushort_t* convWT = (ushort_t*)p; p += (size_t)256*1280*2;
  ushort_t* w1WT   = (ushort_t*)p; p += (size_t)1024*512*2;
  ushort_t* w2WT   = (ushort_t*)p; p += (size_t)1024*1024*2;
  float* ltp = (float*)p; p += (size_t)MS*4;
  float* act = (float*)p; p += (size_t)MS*4;
  float* tsc = (float*)p; p += (size_t)MP*4;
  unsigned* mx = (unsigned*)p; p += 256;
  float* carryL = (float*)p; p += (size_t)NB*2*NCH*3*DD*4;
  float* carryI = (float*)p; p += (size_t)NB*2*NCH*3*DD*4;
  float* scal   = (float*)p; p += (size_t)NB*2*NCH*2*4;

  dim3 b256(256), b64(64);

  { dim3 g(256/64, 256/64);   k_wt<<<g, b256, 0, stream>>>(itW,  itWT,  256, 256); }
  { dim3 g(1280/64, 256/64);  k_wt<<<g, b256, 0, stream>>>(convW,convWT,1280,256); }
  { dim3 g(512/64, 1024/64);  k_wt<<<g, b256, 0, stream>>>(w1W,  w1WT,  512, 1024); }
  { dim3 g(1024/64, 1024/64); k_wt<<<g, b256, 0, stream>>>(w2W,  w2WT,  1024,1024); }

  k_build_seq0<<<MS, 256, 0, stream>>>(seq_in, START, END, seq0);
  { int nwg = (256/128)*(MP/128);
    k_mgemm<0,0,0><<<nwg, b256, 0, stream>>>(seq0, itWT, itb, preLN, nullptr, nullptr, nullptr, MP, 256, 256); }
  k_ln<<<MS, 256, 0, stream>>>(preLN, lng, lnb, seq, cc);
  k_init_state<<<(MS+255)/256, 256, 0, stream>>>(ltp, act);

  for (int step=0; step<NSTEPS; ++step){
    { dim3 g(NB, 4*NCH, 2);
      k_scanchunk<0><<<g, b64, 0, stream>>>(cc, ltp, act, yes_t, no_t, ws5, cc, carryL, scal); }
    { dim3 g(NB, 4, 2);
      k_scancomb<<<g, b64, 0, stream>>>(carryL, carryI, scal, tsc, scb, mx); }
    { dim3 g(NB, 4*NCH, 2);
      k_scanchunk<1><<<g, b64, 0, stream>>>(cc, ltp, act, yes_t, no_t, ws5, cc, carryI, scal); }
    // conv + fused score
    { int nwg = (256/128)*(MP/128);
      k_mgemm<0,0,1><<<nwg, b256, 0, stream>>>(ws5, convWT, convb, nullptr, nullptr, scW, tsc, MP, 256, 5*DD); }
    k_maxred<<<32, b256, 0, stream>>>(tsc, mx);
    // inter = gelu(cc@w1W + w1b)  bf16
    { int nwg = (HH/128)*(MP/128);
      k_mgemm<1,1,0><<<nwg, b256, 0, stream>>>(cc, w1WT, w1b, nullptr, inter, nullptr, nullptr, MP, HH, 2*DD); }
    // contents = inter@w2W + w2b  bf16
    { int nwg = (HH/128)*(MP/128);
      k_mgemm<0,1,0><<<nwg, b256, 0, stream>>>(inter, w2WT, w2b, nullptr, contents, nullptr, nullptr, MP, HH, HH); }
    k_epi<<<MS, 256, 0, stream>>>(contents, tsc, mx, lng, lnb, seq, cc, ltp);
    k_actup<<<NB, b64, 0, stream>>>(ltp, act);
  }
  hipMemcpyAsync(d_out, seq, (size_t)out_size*sizeof(float), hipMemcpyDeviceToDevice, stream);
}

// Round 7
// 1375.978 us; speedup vs baseline: 4.8634x; 1.0203x over previous
//
#include <hip/hip_runtime.h>
#include <math.h>

#define NB 32
#define SS 512
#define S2 514
#define DD 256
#define HH 1024
#define MS (NB*S2)                     // 16448 real rows
#define MP 16512                       // padded to 129*128 for 128-tile GEMM
#define EPSF 1e-9f
#define NSTEPS 6
#define NCH 9                          // scan chunks of 64 rows

typedef unsigned short ushort_t;
typedef __attribute__((ext_vector_type(8))) short short8;
typedef __attribute__((ext_vector_type(4))) float f32x4;

__device__ __forceinline__ float gelu_f(float x){
  float t = tanhf(0.7978845608028654f*(x + 0.044715f*x*x*x));
  return 0.5f*x*(1.f+t);
}
__device__ __forceinline__ float sigmoid_f(float x){ return 1.f/(1.f+expf(-x)); }
__device__ __forceinline__ ushort_t f2bf(float f){
  unsigned u = __float_as_uint(f);
  u += 0x7fffu + ((u>>16)&1u);        // RNE
  return (ushort_t)(u>>16);
}
__device__ __forceinline__ float bf2f(ushort_t b){
  return __uint_as_float(((unsigned)b)<<16);
}
__device__ __forceinline__ void gload_lds16(const void* g, void* l){
  __builtin_amdgcn_global_load_lds((const __attribute__((address_space(1))) void*)g,
                                   (__attribute__((address_space(3))) void*)l, 16, 0, 0);
}

// ---------------- weight transpose + bf16 convert: WT[n][k] = W[k][n] ----------------
__global__ __launch_bounds__(256) void k_wt(const float* __restrict__ W, ushort_t* __restrict__ WT,
                                            int K, int N){
  __shared__ float t[64][65];
  int k0 = blockIdx.x*64, n0 = blockIdx.y*64;
  int tx = threadIdx.x & 63, ty = threadIdx.x >> 6;
#pragma unroll
  for (int i=ty;i<64;i+=4) t[i][tx] = W[(size_t)(k0+i)*N + n0 + tx];
  __syncthreads();
#pragma unroll
  for (int i=ty;i<64;i+=4) WT[(size_t)(n0+i)*K + k0 + tx] = f2bf(t[tx][i]);
}

// ---------------- build padded seq0 in bf16 ----------------
__global__ void k_build_seq0(const float* __restrict__ seq_in, const float* __restrict__ START,
                             const float* __restrict__ END, ushort_t* __restrict__ out){
  int m = blockIdx.x; int d = threadIdx.x;
  int s = m % S2; int b = m / S2;
  float v;
  if (s == 0)        v = START[d];
  else if (s <= SS)  v = seq_in[((size_t)(b*SS + (s-1)))*DD + d];
  else               v = END[d];
  out[(size_t)m*DD + d] = f2bf(v);
}

__global__ void k_init_state(float* __restrict__ ltp, float* __restrict__ act){
  int i = blockIdx.x*256 + threadIdx.x;
  if (i < MS){ ltp[i]=0.f; act[i]=1.f; }
}

// ---------------- MFMA bf16 GEMM: 128x128 tile, BK=32, double-buffered pipeline ------
// T3-minimum 2-phase pipeline: stage(t+1) issued BEFORE compute(t); one raw
// {vmcnt(0); s_barrier} per K-step (never __syncthreads -> no full drain before issue).
// LDS XOR swizzle (both-sides): read slot (rhi+(row>>1))&3, staged from pre-swizzled
// global col ((l&3)-(l>>3))&3 -> conflict-free ds_read_b128 (verified 0 at BK=64 analog).
// Grid: flat, bijective XCD chunking (m204) so N-blocks sharing an A-panel co-locate.
// SCORE=1: no C write; epilogue sums gelu(v)*scW per row, atomicAdd into tsc.
template<int ACT, int OUTBF, int SCORE>
__global__ __launch_bounds__(256) void k_mgemm(const ushort_t* __restrict__ A,
    const ushort_t* __restrict__ BT, const float* __restrict__ bias,
    float* __restrict__ Cf, ushort_t* __restrict__ Cb,
    const float* __restrict__ scW, float* __restrict__ tsc,
    int M, int N, int K)
{
  __shared__ __align__(16) ushort_t Asm[2][128*32];   // [buf][row][k] (slot-swizzled)
  __shared__ __align__(16) ushort_t Bsm[2][128*32];
  const int tid = threadIdx.x;
  const int lane = tid & 63, wid = tid >> 6;

  // bijective XCD swizzle
  const int nwg = gridDim.x, f = blockIdx.x;
  const int q = nwg >> 3, r = nwg & 7;
  const int x = f & 7, jj = f >> 3;
  const int logical = (x < r ? x*(q+1) : r*(q+1) + (x-r)*q) + jj;
  const int NX = N >> 7;
  const int bx = logical % NX, by = logical / NX;
  const int m0 = by * 128, n0 = bx * 128;
  const int wr = (wid>>1)*64, wc = (wid&1)*64;

  f32x4 acc[4][4];
#pragma unroll
  for (int i=0;i<4;i++)
#pragma unroll
    for (int j=0;j<4;j++) acc[i][j] = (f32x4){0.f,0.f,0.f,0.f};

  // staging geometry: 8 chunks of 1KB per matrix (16 rows x 32 k each); wave stages
  // chunks {wid, wid+4}. lane covers row lane>>2, swizzled source col ((l&3)-(l>>3))&3.
  const int srow4 = lane >> 2;
  const int scol = ((((lane&3) - (lane>>3)) & 3) << 3);
  const int rrow = lane & 15, rhi = lane >> 4;

  const int nt = K >> 5;
  int cur = 0;

  // prologue: stage tile 0
#pragma unroll
  for (int tt=0; tt<2; ++tt){
    int c = wid + 4*tt;
    gload_lds16(A  + (size_t)(m0 + c*16 + srow4)*K + scol, &Asm[0][c*512]);
    gload_lds16(BT + (size_t)(n0 + c*16 + srow4)*K + scol, &Bsm[0][c*512]);
  }
  asm volatile("s_waitcnt vmcnt(0)\n\ts_barrier" ::: "memory");

  for (int t=0; t<nt; ++t){
    if (t+1 < nt){
      const int k1 = (t+1) << 5;
#pragma unroll
      for (int tt=0; tt<2; ++tt){
        int c = wid + 4*tt;
        gload_lds16(A  + (size_t)(m0 + c*16 + srow4)*K + k1 + scol, &Asm[cur^1][c*512]);
        gload_lds16(BT + (size_t)(n0 + c*16 + srow4)*K + k1 + scol, &Bsm[cur^1][c*512]);
      }
    }
    short8 a[4], b[4];
#pragma unroll
    for (int i=0;i<4;i++){
      int ra = wr + i*16 + rrow;
      int sa = ((rhi + (ra>>1)) & 3) << 3;
      a[i] = *reinterpret_cast<const short8*>(&Asm[cur][ra*32 + sa]);
      int rb = wc + i*16 + rrow;
      int sb = ((rhi + (rb>>1)) & 3) << 3;
      b[i] = *reinterpret_cast<const short8*>(&Bsm[cur][rb*32 + sb]);
    }
    __builtin_amdgcn_s_setprio(1);
#pragma unroll
    for (int i=0;i<4;i++)
#pragma unroll
      for (int j=0;j<4;j++)
        acc[i][j] = __builtin_amdgcn_mfma_f32_16x16x32_bf16(a[i], b[j], acc[i][j], 0,0,0);
    __builtin_amdgcn_s_setprio(0);
    if (t+1 < nt){
      asm volatile("s_waitcnt vmcnt(0)\n\ts_barrier" ::: "memory");
      cur ^= 1;
    }
  }

  if (SCORE){
#pragma unroll
    for (int i=0;i<4;i++){
#pragma unroll
      for (int rreg=0;rreg<4;rreg++){
        float rs = 0.f;
#pragma unroll
        for (int j=0;j<4;j++){
          int gn = n0 + wc + j*16 + (lane&15);
          float v = gelu_f(acc[i][j][rreg] + bias[gn]);
          rs += v * scW[gn];
        }
        rs += __shfl_xor(rs,1); rs += __shfl_xor(rs,2);
        rs += __shfl_xor(rs,4); rs += __shfl_xor(rs,8);
        if ((lane&15)==0){
          int gm = m0 + wr + i*16 + (lane>>4)*4 + rreg;
          atomicAdd(&tsc[gm], rs);
        }
      }
    }
  } else {
#pragma unroll
    for (int i=0;i<4;i++){
#pragma unroll
      for (int rreg=0;rreg<4;rreg++){
        size_t gm = m0 + wr + i*16 + (lane>>4)*4 + rreg;
#pragma unroll
        for (int j=0;j<4;j++){
          int gn = n0 + wc + j*16 + (lane&15);
          float v = acc[i][j][rreg] + bias[gn];
          if (ACT==1) v = gelu_f(v);
          if (OUTBF) Cb[gm*N + gn] = f2bf(v);
          else       Cf[gm*N + gn] = v;
        }
      }
    }
  }
}

// ---------------- LayerNorm (init) ----------------
__global__ __launch_bounds__(256) void k_ln(const float* __restrict__ x, const float* __restrict__ g,
                                            const float* __restrict__ bta, float* __restrict__ out,
                                            ushort_t* __restrict__ cc){
  __shared__ float red[8];
  int m = blockIdx.x, d = threadIdx.x;
  float v = x[(size_t)m*DD + d];
  float s1 = v, s2 = v*v;
  for (int off=32; off; off>>=1){ s1 += __shfl_down(s1,off); s2 += __shfl_down(s2,off); }
  int wid = d >> 6;
  if ((d&63)==0){ red[wid*2]=s1; red[wid*2+1]=s2; }
  __syncthreads();
  float sum = red[0]+red[2]+red[4]+red[6];
  float sq  = red[1]+red[3]+red[5]+red[7];
  float mean = sum * (1.f/DD);
  float var  = sq  * (1.f/DD) - mean*mean;
  float inv  = rsqrtf(fmaxf(var,0.f) + 1e-5f);
  float o = (v-mean)*inv*g[d] + bta[d];
  out[(size_t)m*DD + d] = o;
  cc[(size_t)m*(2*DD) + DD + d] = f2bf(o);
}

// ---------------- chunked parallel scan ----------------
template<int PASS>
__global__ __launch_bounds__(64) void k_scanchunk(
    const ushort_t* __restrict__ ccp, const float* __restrict__ ltpp, const float* __restrict__ actp,
    const float* __restrict__ yes_t, const float* __restrict__ no_t,
    ushort_t* __restrict__ ws5, ushort_t* __restrict__ ccw,
    float* __restrict__ carry, float* __restrict__ scal)
{
  __shared__ ushort_t s_sv[66][64];
  __shared__ float s_lt[66], s_ac[66];
  const int b = blockIdx.x, dg = blockIdx.y & 3, ck = blockIdx.y >> 2, dir = blockIdx.z, t = threadIdx.x;
  int st, ln;
  if (dir==0){ st = ck*64; ln = (S2 - st < 64) ? (S2 - st) : 64; }
  else { int hi = (S2-1) - ck*64; st = (hi-63 < 0) ? 0 : hi-63; ln = hi - st + 1; }
  const int lo = st - 1;
  const size_t mb = (size_t)b*S2;
  for (int r=0; r<ln+2; ++r){
    int gr = lo + r; gr = gr < 0 ? 0 : (gr > S2-1 ? S2-1 : gr);
    s_sv[r][t] = ccp[(mb+gr)*(2*DD) + DD + (dg<<6) + t];
  }
  for (int r=t; r<ln+2; r+=64){
    int gr = lo + r; gr = gr < 0 ? 0 : (gr > S2-1 ? S2-1 : gr);
    s_lt[r] = ltpp[mb+gr]; s_ac[r] = actp[mb+gr];
  }
  __syncthreads();
  const int d = (dg<<6)+t;
  const float yv = yes_t[d], nv = no_t[d];
  float ci1=0.f, ci2=0.f, cic=0.f;
  const size_t cbase = (((size_t)b*2+dir)*NCH + ck)*3*DD;
  if (PASS==1){
    ci1 = carry[cbase+d]; ci2 = carry[cbase+DD+d];
    if (dir==0) cic = carry[cbase+2*DD+d];
  }
  float A=1.f, Bs=0.f, z1=0.f, z2=0.f, zc=0.f;
  const int pr = (dir==0) ? 0 : (ln+1);
  float svp = bf2f(s_sv[pr][t]); float ltpv = s_lt[pr];
  float pb = svp + ltpv*yv + (1.f-ltpv)*nv, ps = svp, pa = s_ac[pr];
  for (int i=0;i<ln;i++){
    const int r = (dir==0) ? (i+1) : (ln-i);
    const int s = (dir==0) ? (st+i) : (st+ln-1-i);
    float sv = bf2f(s_sv[r][t]); float lt = s_lt[r]; float av = s_ac[r];
    float bse = sv + lt*yv + (1.f-lt)*nv;
    bool upd = (dir==0) ? (s>0) : (s<S2-1);
    if (upd){
      float c = pa, fc = 1.f-c+EPSF;
      z2 = c*z1 + fc*z2;
      z1 = c*pb + fc*z1;
      zc = c*ps + fc*zc;
      Bs = c*A + fc*Bs; A = fc*A;
    }
    if (PASS==1){
      size_t m = mb + s; size_t w5 = m*(5*DD);
      float Z1 = z1 + A*ci1, Z2 = z2 + Bs*ci1 + A*ci2;
      if (dir==0){
        float Zc = zc + A*cic;
        ws5[w5 + d]        = f2bf(Z2);
        ws5[w5 + DD + d]   = f2bf(Z1);
        ws5[w5 + 2*DD + d] = f2bf(bse);
        ccw[m*(2*DD) + d]  = f2bf(Zc);
      } else {
        ws5[w5 + 3*DD + d] = f2bf(Z1);
        ws5[w5 + 4*DD + d] = f2bf(Z2);
      }
    }
    pb=bse; ps=sv; pa=av;
  }
  if (PASS==0){
    carry[cbase+d] = z1; carry[cbase+DD+d] = z2;
    if (dir==0) carry[cbase+2*DD+d] = zc;
    if (dg==0 && t==0){ size_t sb = (((size_t)b*2+dir)*NCH+ck)*2; scal[sb]=A; scal[sb+1]=Bs; }
  }
}

// combine carries across chunks; also pre-inits tsc=scb and mx=0.
__global__ __launch_bounds__(64) void k_scancomb(const float* __restrict__ cl, float* __restrict__ cin,
    const float* __restrict__ scal, float* __restrict__ tscp, const float* __restrict__ scb,
    unsigned* __restrict__ mxp)
{
  const int b = blockIdx.x, dg = blockIdx.y, dir = blockIdx.z, t = threadIdx.x;
  const int d = (dg<<6)+t;
  if (dir==0 && dg==0){
    float sbv = scb[0];
    for (int i=t;i<S2;i+=64) tscp[(size_t)b*S2+i]=sbv;
    if (b==0 && t==0) *mxp = 0u;
  }
  float s1=0.f,s2=0.f,sc=0.f;
  for (int k=0;k<NCH;k++){
    size_t cbase = (((size_t)b*2+dir)*NCH+k)*3*DD;
    cin[cbase+d]=s1; cin[cbase+DD+d]=s2; if(dir==0) cin[cbase+2*DD+d]=sc;
    size_t sb = (((size_t)b*2+dir)*NCH+k)*2;
    float A = scal[sb], Bs = scal[sb+1];
    float l1 = cl[cbase+d], l2 = cl[cbase+DD+d];
    float ns1 = l1 + A*s1;
    float ns2 = l2 + Bs*s1 + A*s2;
    if (dir==0){ float lcv = cl[cbase+2*DD+d]; sc = lcv + A*sc; }
    s1=ns1; s2=ns2;
  }
}

// ---------------- global max of tsc (clamped at 0) ----------------
__global__ __launch_bounds__(256) void k_maxred(const float* __restrict__ tsc, unsigned* __restrict__ mx){
  __shared__ float red[4];
  int t0 = blockIdx.x*256 + threadIdx.x;
  float v = 0.f;
  for (int i=t0; i<MS; i+=256*32) v = fmaxf(v, tsc[i]);
  for (int off=32; off; off>>=1) v = fmaxf(v, __shfl_down(v,off));
  if ((threadIdx.x&63)==0) red[threadIdx.x>>6]=v;
  __syncthreads();
  if (threadIdx.x==0){
    float r = fmaxf(fmaxf(red[0],red[1]),fmaxf(red[2],red[3]));
    atomicMax(mx, __float_as_uint(r));
  }
}

// ---------------- tp + gates + LN + gated update ----------------
__global__ __launch_bounds__(256) void k_epi(const ushort_t* __restrict__ contents,
     const float* __restrict__ tsc, const unsigned* __restrict__ mx,
     const float* __restrict__ g, const float* __restrict__ bta,
     float* __restrict__ seq, ushort_t* __restrict__ cc, float* __restrict__ ltp){
  __shared__ float red[8];
  int m = blockIdx.x, d = threadIdx.x;
  int s = m % S2;
  float M = __uint_as_float(*mx);
  float sel = (s >= 1 && s <= SS-1) ? 1.f : 0.f;
  float et = expf(tsc[m]-M)*sel;
  float tpv = et/(et+expf(-M)+EPSF);
  if (d==0) ltp[m] = tpv;

  size_t b4 = (size_t)m*HH;
  float lcv = bf2f(cc[(size_t)m*(2*DD) + d]);
  float sv  = seq[(size_t)m*DD+d];
  float g0 = sigmoid_f(bf2f(contents[b4 + d]));
  float g1 = sigmoid_f(bf2f(contents[b4 + DD + d]));
  float g2 = sigmoid_f(bf2f(contents[b4 + 2*DD + d]));
  float pv = bf2f(contents[b4 + 3*DD + d]);
  float xv = g0*lcv + g1*sv + g2*pv;
  float s1=xv, s2=xv*xv;
  for (int off=32; off; off>>=1){ s1 += __shfl_down(s1,off); s2 += __shfl_down(s2,off); }
  int wid = d>>6;
  if ((d&63)==0){ red[wid*2]=s1; red[wid*2+1]=s2; }
  __syncthreads();
  float sum=red[0]+red[2]+red[4]+red[6];
  float sq =red[1]+red[3]+red[5]+red[7];
  float mean = sum*(1.f/DD);
  float var  = sq *(1.f/DD)-mean*mean;
  float inv = rsqrtf(fmaxf(var,0.f)+1e-5f);
  float comp = (xv-mean)*inv*g[d] + bta[d];
  float o = tpv*comp + (1.f-tpv)*sv;
  seq[(size_t)m*DD+d] = o;
  cc[(size_t)m*(2*DD) + DD + d] = f2bf(o);
}

// ---------------- active update: lane-segmented affine scan + shfl combine ----------
__global__ __launch_bounds__(64) void k_actup(const float* __restrict__ tp, float* __restrict__ act){
  __shared__ float s_a[S2], s_t[S2], s_o[S2];
  int b = blockIdx.x, t = threadIdx.x;
  for (int s=t;s<S2;s+=64){ s_a[s]=act[(size_t)b*S2+s]; s_t[s]=tp[(size_t)b*S2+s]; }
  __syncthreads();
  int hi = (S2-1) - 9*t;
  int lo = hi - 8; if (lo < 0) lo = 0;
  float A=1.f, Bv=0.f;
  if (hi >= 0){
    for (int s=hi; s>=lo; --s){
      float fc = 1.f - s_a[s] + EPSF;
      Bv = s_t[s] + fc*Bv; A = fc*A;
    }
  }
  float Ai=A, Bi=Bv;
  for (int off=1; off<64; off<<=1){
    float Ao = __shfl_up(Ai, off), Bo = __shfl_up(Bi, off);
    if (t >= off){ Bi = Bi + Ai*Bo; Ai = Ai*Ao; }
  }
  float uin = __shfl_up(Bi, 1); if (t==0) uin = 0.f;
  if (hi >= 0){
    float u = uin;
    for (int s=hi; s>=lo; --s){
      float a = s_a[s];
      float na = a*(1.f - a*u);
      s_o[s] = fminf(fmaxf(na,0.f),1.f);
      u = s_t[s] + (1.f - a + EPSF)*u;
    }
  }
  __syncthreads();
  for (int s=t;s<S2;s+=64) act[(size_t)b*S2+s]=s_o[s];
}

extern "C" void kernel_launch(void* const* d_in, const int* in_sizes, int n_in,
                              void* d_out, int out_size, void* d_ws, size_t ws_size,
                              hipStream_t stream){
  const float* seq_in = (const float*)d_in[0];
  const float* START = (const float*)d_in[2];
  const float* END   = (const float*)d_in[3];
  const float* yes_t = (const float*)d_in[4];
  const float* no_t  = (const float*)d_in[5];
  const float* convW = (const float*)d_in[6];
  const float* convb = (const float*)d_in[7];
  const float* scW   = (const float*)d_in[8];
  const float* scb   = (const float*)d_in[9];
  const float* itW   = (const float*)d_in[10];
  const float* itb   = (const float*)d_in[11];
  const float* w1W   = (const float*)d_in[12];
  const float* w1b   = (const float*)d_in[13];
  const float* w2W   = (const float*)d_in[14];
  const float* w2b   = (const float*)d_in[15];
  const float* lng   = (const float*)d_in[16];
  const float* lnb   = (const float*)d_in[17];

  char* p = (char*)d_ws;
  float*    seq  = (float*)p;    p += (size_t)MP*DD*4;          // f32 state
  ushort_t* cc   = (ushort_t*)p; p += (size_t)MP*(2*DD)*2;      // bf16 [lc|seq]
  ushort_t* ws5      = (ushort_t*)p;
  ushort_t* contents = (ushort_t*)p;
  float*    preLN    = (float*)p; p += (size_t)MP*2560;
  ushort_t* inter = (ushort_t*)p;
  ushort_t* seq0  = (ushort_t*)p; p += (size_t)MP*2048;
  ushort_t* itWT   = (ushort_t*)p; p += (size_t)256*256*2;
  ushort_t* convWT = (ushort_t*)p; p += (size_t)256*1280*2;
  ushort_t* w1WT   = (ushort_t*)p; p += (size_t)1024*512*2;
  ushort_t* w2WT   = (ushort_t*)p; p += (size_t)1024*1024*2;
  float* ltp = (float*)p; p += (size_t)MS*4;
  float* act = (float*)p; p += (size_t)MS*4;
  float* tsc = (float*)p; p += (size_t)MP*4;
  unsigned* mx = (unsigned*)p; p += 256;
  float* carryL = (float*)p; p += (size_t)NB*2*NCH*3*DD*4;
  float* carryI = (float*)p; p += (size_t)NB*2*NCH*3*DD*4;
  float* scal   = (float*)p; p += (size_t)NB*2*NCH*2*4;

  dim3 b256(256), b64(64);

  { dim3 g(256/64, 256/64);   k_wt<<<g, b256, 0, stream>>>(itW,  itWT,  256, 256); }
  { dim3 g(1280/64, 256/64);  k_wt<<<g, b256, 0, stream>>>(convW,convWT,1280,256); }
  { dim3 g(512/64, 1024/64);  k_wt<<<g, b256, 0, stream>>>(w1W,  w1WT,  512, 1024); }
  { dim3 g(1024/64, 1024/64); k_wt<<<g, b256, 0, stream>>>(w2W,  w2WT,  1024,1024); }

  k_build_seq0<<<MS, 256, 0, stream>>>(seq_in, START, END, seq0);
  { int nwg = (256/128)*(MP/128);
    k_mgemm<0,0,0><<<nwg, b256, 0, stream>>>(seq0, itWT, itb, preLN, nullptr, nullptr, nullptr, MP, 256, 256); }
  k_ln<<<MS, 256, 0, stream>>>(preLN, lng, lnb, seq, cc);
  k_init_state<<<(MS+255)/256, 256, 0, stream>>>(ltp, act);

  for (int step=0; step<NSTEPS; ++step){
    { dim3 g(NB, 4*NCH, 2);
      k_scanchunk<0><<<g, b64, 0, stream>>>(cc, ltp, act, yes_t, no_t, ws5, cc, carryL, scal); }
    { dim3 g(NB, 4, 2);
      k_scancomb<<<g, b64, 0, stream>>>(carryL, carryI, scal, tsc, scb, mx); }
    { dim3 g(NB, 4*NCH, 2);
      k_scanchunk<1><<<g, b64, 0, stream>>>(cc, ltp, act, yes_t, no_t, ws5, cc, carryI, scal); }
    // conv + fused score
    { int nwg = (256/128)*(MP/128);
      k_mgemm<0,0,1><<<nwg, b256, 0, stream>>>(ws5, convWT, convb, nullptr, nullptr, scW, tsc, MP, 256, 5*DD); }
    k_maxred<<<32, b256, 0, stream>>>(tsc, mx);
    // inter = gelu(cc@w1W + w1b)  bf16
    { int nwg = (HH/128)*(MP/128);
      k_mgemm<1,1,0><<<nwg, b256, 0, stream>>>(cc, w1WT, w1b, nullptr, inter, nullptr, nullptr, MP, HH, 2*DD); }
    // contents = inter@w2W + w2b  bf16
    { int nwg = (HH/128)*(MP/128);
      k_mgemm<0,1,0><<<nwg, b256, 0, stream>>>(inter, w2WT, w2b, nullptr, contents, nullptr, nullptr, MP, HH, HH); }
    k_epi<<<MS, 256, 0, stream>>>(contents, tsc, mx, lng, lnb, seq, cc, ltp);
    k_actup<<<NB, b64, 0, stream>>>(ltp, act);
  }
  hipMemcpyAsync(d_out, seq, (size_t)out_size*sizeof(float), hipMemcpyDeviceToDevice, stream);
}